// Round 1
// baseline (301.116 us; speedup 1.0000x reference)
//
#include <hip/hip_runtime.h>
#include <hip/hip_bf16.h>

// Quantized CIFAR-10 net, fully fused: one workgroup per image, all
// intermediates live in LDS as small integer codes (exact arithmetic —
// every tensor value is a small int times a power of two, so fp32
// accumulation is exact and order-independent => absmax should be 0).
//
// Weight quantization is done once per launch by prep_weights into d_ws
// (dequantized fp32 codes, 46564 floats = 186 KB, fully L2-resident).

// ---- workspace layout (float offsets) ----
#define OFF_W0   0       // (3,3)      9
#define OFF_DW1  9       // (3,9)      27
#define OFF_PW1  36      // (32,3)     96
#define OFF_DW2  132     // (32,9)     288
#define OFF_PW2  420     // (64,32)    2048
#define OFF_DW3  2468    // (64,9)     576
#define OFF_PW3  3044    // (128,64)   8192
#define OFF_WC1  11236   // (256,128)  32768
#define OFF_WC2  44004   // (10,256)   2560
#define W_TOTAL  46564

__global__ __launch_bounds__(256) void prep_weights(
    const float* __restrict__ w0,  const float* __restrict__ dw1,
    const float* __restrict__ pw1, const float* __restrict__ dw2,
    const float* __restrict__ pw2, const float* __restrict__ dw3,
    const float* __restrict__ pw3, const float* __restrict__ wc1,
    const float* __restrict__ wc2, float* __restrict__ ws) {
  int t = blockIdx.x * blockDim.x + threadIdx.x;
  if (t >= W_TOTAL) return;
  float w;
  float lo = -8.f, hi = 7.f;             // 4-bit signed weights
  if (t < OFF_DW1)      { w = w0[t];            lo = -128.f; hi = 127.f; } // 8-bit
  else if (t < OFF_PW1)   w = dw1[t - OFF_DW1];
  else if (t < OFF_DW2)   w = pw1[t - OFF_PW1];
  else if (t < OFF_PW2)   w = dw2[t - OFF_DW2];
  else if (t < OFF_DW3)   w = pw2[t - OFF_PW2];
  else if (t < OFF_PW3)   w = dw3[t - OFF_DW3];
  else if (t < OFF_WC1)   w = pw3[t - OFF_PW3];
  else if (t < OFF_WC2)   w = wc1[t - OFF_WC1];
  else                    w = wc2[t - OFF_WC2];
  // S_W = 0.25 for all weights; dequantized value stored
  ws[t] = fminf(fmaxf(rintf(w * 4.f), lo), hi) * 0.25f;
}

// quant helpers (round-half-even == jnp.round == rintf)
__device__ __forceinline__ float q_signed4(float v) {          // codes -8..7
  return fminf(fmaxf(rintf(v * 2.f), -8.f), 7.f);              // scale 0.5
}
__device__ __forceinline__ float qrelu_code(float v) {         // codes 0..15
  return fminf(fmaxf(rintf(fmaxf(v, 0.f) * 4.f), 0.f), 15.f);  // scale 0.25
}
__device__ __forceinline__ float requant_code(float rcode) {   // relu code -> next-layer 4b code 0..7
  return fminf(rintf(rcode * 0.5f), 7.f);                      // (r*0.25)/0.5
}

__global__ __launch_bounds__(256) void fused_net(
    const float* __restrict__ x,     // (1024,3,32,32)
    const float* __restrict__ wq,    // dequantized weights (see offsets)
    float* __restrict__ out)         // (1024,10)
{
  const int img = blockIdx.x;
  const int tid = threadIdx.x;

  const float* w0q  = wq + OFF_W0;
  const float* dw1q = wq + OFF_DW1;
  const float* pw1q = wq + OFF_PW1;
  const float* dw2q = wq + OFF_DW2;
  const float* pw2q = wq + OFF_PW2;
  const float* dw3q = wq + OFF_DW3;
  const float* pw3q = wq + OFF_PW3;
  const float* wc1q = wq + OFF_WC1;
  const float* wc2q = wq + OFF_WC2;

  __shared__ signed char s_b[3 * 1024];   // dw1 input codes  (3,32,32)
  __shared__ signed char s_c[3 * 1024];   // pw1 input codes  (3,32,32)
  __shared__ signed char s_e[32 * 256];   // dw2 input codes  (32,16,16)
  __shared__ signed char s_f[32 * 256];   // pw2 input codes  (32,16,16)
  __shared__ signed char s_g[64 * 64];    // dw3 input codes  (64,8,8)
  __shared__ signed char s_h[64 * 64];    // pw3 input codes  (64,8,8)
  __shared__ float       s_w2[2048];      // pw2 dequant weights in LDS
  __shared__ signed char s_m[128];        // fc1 input codes
  __shared__ signed char s_n[256];        // fc2 input codes
  __shared__ float       s_red[256];      // reduction scratch
  // total ~40.3 KB -> 4 blocks/CU

  // stash pw2 weights in LDS (used heavily in stage 2b)
  for (int i = tid; i < 2048; i += 256) s_w2[i] = pw2q[i];

  // ---- stage 0+1a: input quant (8b) + 1x1 conv w0 + dw1-input quant ----
  {
    const float* xim = x + (size_t)img * 3072;
    float w0r[9];
#pragma unroll
    for (int i = 0; i < 9; i++) w0r[i] = w0q[i];
    for (int p = tid; p < 1024; p += 256) {
      float a0 = fminf(fmaxf(rintf(xim[p]        * 16.f), -128.f), 127.f) * 0.0625f;
      float a1 = fminf(fmaxf(rintf(xim[1024 + p] * 16.f), -128.f), 127.f) * 0.0625f;
      float a2 = fminf(fmaxf(rintf(xim[2048 + p] * 16.f), -128.f), 127.f) * 0.0625f;
#pragma unroll
      for (int o = 0; o < 3; o++) {
        float h = a0 * w0r[o * 3] + a1 * w0r[o * 3 + 1] + a2 * w0r[o * 3 + 2];
        s_b[o * 1024 + p] = (signed char)q_signed4(h);
      }
    }
  }
  __syncthreads();

  // ---- stage 1b: depthwise 3x3 (3ch, 32x32, pad 1) + pw1-input quant ----
  for (int idx = tid; idx < 3072; idx += 256) {
    int c = idx >> 10, p = idx & 1023, y = p >> 5, xx = p & 31;
    const float* wk = dw1q + c * 9;
    float acc = 0.f;
#pragma unroll
    for (int ky = 0; ky < 3; ky++) {
      int yy = y + ky - 1;
      if (yy < 0 || yy > 31) continue;
#pragma unroll
      for (int kx = 0; kx < 3; kx++) {
        int x2 = xx + kx - 1;
        if (x2 < 0 || x2 > 31) continue;
        acc += (float)s_b[c * 1024 + yy * 32 + x2] * wk[ky * 3 + kx];
      }
    }
    s_c[idx] = (signed char)q_signed4(0.5f * acc);
  }
  __syncthreads();

  // ---- stage 1c: pw1 (3->32) + qrelu4 + maxpool2 + dw2-input quant ----
  for (int idx = tid; idx < 8192; idx += 256) {
    int o = idx >> 8, pos = idx & 255, py = pos >> 4, px = pos & 15;
    float wa = pw1q[o * 3], wb = pw1q[o * 3 + 1], wc = pw1q[o * 3 + 2];
    float mx = 0.f;
#pragma unroll
    for (int dy = 0; dy < 2; dy++)
#pragma unroll
      for (int dx = 0; dx < 2; dx++) {
        int sp = (2 * py + dy) * 32 + (2 * px + dx);
        float v = 0.5f * ((float)s_c[sp] * wa + (float)s_c[1024 + sp] * wb +
                          (float)s_c[2048 + sp] * wc);
        mx = fmaxf(mx, qrelu_code(v));
      }
    s_e[idx] = (signed char)requant_code(mx);
  }
  __syncthreads();

  // ---- stage 2a: depthwise 3x3 (32ch, 16x16, pad 1) + pw2-input quant ----
  for (int idx = tid; idx < 8192; idx += 256) {
    int c = idx >> 8, pos = idx & 255, y = pos >> 4, xx = pos & 15;
    const float* wk = dw2q + c * 9;
    float acc = 0.f;
#pragma unroll
    for (int ky = 0; ky < 3; ky++) {
      int yy = y + ky - 1;
      if (yy < 0 || yy > 15) continue;
#pragma unroll
      for (int kx = 0; kx < 3; kx++) {
        int x2 = xx + kx - 1;
        if (x2 < 0 || x2 > 15) continue;
        acc += (float)s_e[c * 256 + yy * 16 + x2] * wk[ky * 3 + kx];
      }
    }
    s_f[idx] = (signed char)q_signed4(0.5f * acc);
  }
  __syncthreads();

  // ---- stage 2b: pw2 (32->64) + qrelu4 + maxpool2 + dw3-input quant ----
  for (int idx = tid; idx < 4096; idx += 256) {
    int o = idx >> 6, pos = idx & 63, py = pos >> 3, px = pos & 7;
    const float* wr = s_w2 + o * 32;
    float mx = 0.f;
#pragma unroll
    for (int dy = 0; dy < 2; dy++)
#pragma unroll
      for (int dx = 0; dx < 2; dx++) {
        int sp = (2 * py + dy) * 16 + (2 * px + dx);
        float acc = 0.f;
#pragma unroll 8
        for (int i = 0; i < 32; i++)
          acc += (float)s_f[i * 256 + sp] * wr[i];
        mx = fmaxf(mx, qrelu_code(0.5f * acc));
      }
    s_g[idx] = (signed char)requant_code(mx);
  }
  __syncthreads();

  // ---- stage 3a: depthwise 3x3 (64ch, 8x8, pad 1) + pw3-input quant ----
  for (int idx = tid; idx < 4096; idx += 256) {
    int c = idx >> 6, pos = idx & 63, y = pos >> 3, xx = pos & 7;
    const float* wk = dw3q + c * 9;
    float acc = 0.f;
#pragma unroll
    for (int ky = 0; ky < 3; ky++) {
      int yy = y + ky - 1;
      if (yy < 0 || yy > 7) continue;
#pragma unroll
      for (int kx = 0; kx < 3; kx++) {
        int x2 = xx + kx - 1;
        if (x2 < 0 || x2 > 7) continue;
        acc += (float)s_g[c * 64 + yy * 8 + x2] * wk[ky * 3 + kx];
      }
    }
    s_h[idx] = (signed char)q_signed4(0.5f * acc);
  }
  __syncthreads();

  // ---- stage 3b: pw3 (64->128) + qrelu4 + global maxpool + fc1-input quant ----
  {
    int o = tid >> 1, half = tid & 1;     // 2 threads per output channel
    const float* wr = pw3q + o * 64;
    float mx = 0.f;
    for (int spi = 0; spi < 32; spi++) {
      int sp = half * 32 + spi;
      float acc = 0.f;
#pragma unroll
      for (int i = 0; i < 64; i += 4) {
        float4 w4 = *(const float4*)(wr + i);
        acc += (float)s_h[i * 64 + sp] * w4.x
             + (float)s_h[(i + 1) * 64 + sp] * w4.y
             + (float)s_h[(i + 2) * 64 + sp] * w4.z
             + (float)s_h[(i + 3) * 64 + sp] * w4.w;
      }
      mx = fmaxf(mx, qrelu_code(0.5f * acc));
    }
    s_red[tid] = mx;
  }
  __syncthreads();
  if (tid < 128) {
    float mm = fmaxf(s_red[2 * tid], s_red[2 * tid + 1]);
    s_m[tid] = (signed char)requant_code(mm);
  }
  __syncthreads();

  // ---- fc1: 128 -> 256 + qrelu4 + fc2-input quant ----
  {
    const float* wr = wc1q + tid * 128;
    float acc = 0.f;
#pragma unroll 8
    for (int i = 0; i < 128; i += 4) {
      float4 w4 = *(const float4*)(wr + i);
      acc += (float)s_m[i] * w4.x + (float)s_m[i + 1] * w4.y +
             (float)s_m[i + 2] * w4.z + (float)s_m[i + 3] * w4.w;
    }
    float r = qrelu_code(0.5f * acc);
    s_n[tid] = (signed char)requant_code(r);
  }
  __syncthreads();

  // ---- fc2: 256 -> 10 + output int8 quant ----
  {
    int k = tid >> 3, j = tid & 7;
    float partial = 0.f;
    if (k < 10) {
      const float* wr = wc2q + k * 256 + j * 32;
#pragma unroll
      for (int i = 0; i < 32; i += 4) {
        float4 w4 = *(const float4*)(wr + i);
        partial += (float)s_n[j * 32 + i] * w4.x + (float)s_n[j * 32 + i + 1] * w4.y +
                   (float)s_n[j * 32 + i + 2] * w4.z + (float)s_n[j * 32 + i + 3] * w4.w;
      }
    }
    s_red[tid] = partial;
  }
  __syncthreads();
  if (tid < 10) {
    float acc = 0.f;
#pragma unroll
    for (int j = 0; j < 8; j++) acc += s_red[tid * 8 + j];
    float v = 0.5f * acc;
    // fq_signed(v, 2^-4, 8 bits)
    out[(size_t)img * 10 + tid] =
        fminf(fmaxf(rintf(v * 16.f), -128.f), 127.f) * 0.0625f;
  }
}

extern "C" void kernel_launch(void* const* d_in, const int* in_sizes, int n_in,
                              void* d_out, int out_size, void* d_ws, size_t ws_size,
                              hipStream_t stream) {
  const float* x   = (const float*)d_in[0];
  const float* w0  = (const float*)d_in[1];
  const float* dw1 = (const float*)d_in[2];
  const float* pw1 = (const float*)d_in[3];
  const float* dw2 = (const float*)d_in[4];
  const float* pw2 = (const float*)d_in[5];
  const float* dw3 = (const float*)d_in[6];
  const float* pw3 = (const float*)d_in[7];
  const float* wc1 = (const float*)d_in[8];
  const float* wc2 = (const float*)d_in[9];
  float* wsq = (float*)d_ws;   // 46564 floats = 186 KB of scratch
  float* out = (float*)d_out;  // (1024,10,1,1) fp32

  prep_weights<<<(W_TOTAL + 255) / 256, 256, 0, stream>>>(
      w0, dw1, pw1, dw2, pw2, dw3, pw3, wc1, wc2, wsq);
  fused_net<<<1024, 256, 0, stream>>>(x, wsq, out);
}

// Round 2
// 117.457 us; speedup vs baseline: 2.5636x; 2.5636x over previous
//
#include <hip/hip_runtime.h>

// ---- weight workspace layout (int32 units) ----
#define W0i   0       // 9   int codes (8-bit, -128..127)
#define DW1i  9       // 27  int codes (4-bit)
#define PW1i  36      // 96  int codes
#define DW2i  132     // 288 int codes
#define DW3i  420     // 576 int codes
#define PW2p  996     // 512  packed i8x4: [o=0..63][k4=0..7]
#define PW3p  1508    // 2048 packed:     [o=0..127][k4=0..15]
#define WC1p  3556    // 8192 packed:     [o=0..255][k4=0..31]
#define WC2p  11748   // 640  packed:     [o=0..9][k4=0..63]
#define WTOT  12388

__device__ __forceinline__ int iclamp(int v, int lo, int hi) {
  return v < lo ? lo : (v > hi ? hi : v);
}

__device__ __forceinline__ int dot4(int a, int b, int c) {
#if defined(__has_builtin)
#if __has_builtin(__builtin_amdgcn_sdot4)
  return __builtin_amdgcn_sdot4(a, b, c, false);
#else
  c += ((a << 24) >> 24) * ((b << 24) >> 24);
  c += ((a << 16) >> 24) * ((b << 16) >> 24);
  c += ((a <<  8) >> 24) * ((b <<  8) >> 24);
  c += (a >> 24) * (b >> 24);
  return c;
#endif
#else
  c += ((a << 24) >> 24) * ((b << 24) >> 24);
  c += ((a << 16) >> 24) * ((b << 16) >> 24);
  c += ((a <<  8) >> 24) * ((b <<  8) >> 24);
  c += (a >> 24) * (b >> 24);
  return c;
#endif
}

__global__ __launch_bounds__(256) void prep_weights(
    const float* __restrict__ w0,  const float* __restrict__ dw1,
    const float* __restrict__ pw1, const float* __restrict__ dw2,
    const float* __restrict__ pw2, const float* __restrict__ dw3,
    const float* __restrict__ pw3, const float* __restrict__ wc1,
    const float* __restrict__ wc2, int* __restrict__ ws) {
  int t = blockIdx.x * blockDim.x + threadIdx.x;
  if (t >= WTOT) return;
  if (t < PW2p) {
    float w; int lo = -8, hi = 7;
    if (t < DW1i)      { w = w0[t];        lo = -128; hi = 127; }
    else if (t < PW1i)   w = dw1[t - DW1i];
    else if (t < DW2i)   w = pw1[t - PW1i];
    else if (t < DW3i)   w = dw2[t - DW2i];
    else                 w = dw3[t - DW3i];
    ws[t] = iclamp((int)rintf(w * 4.f), lo, hi);   // code = round(w / 0.25)
  } else {
    const float* src;
    if (t < WC1p) {
      if (t < PW3p) src = pw2 + (t - PW2p) * 4;
      else          src = pw3 + (t - PW3p) * 4;
    } else {
      if (t < WC2p) src = wc1 + (t - WC1p) * 4;
      else          src = wc2 + (t - WC2p) * 4;
    }
    int p = 0;
#pragma unroll
    for (int b = 0; b < 4; b++) {
      int c = iclamp((int)rintf(src[b] * 4.f), -8, 7);
      p |= (c & 0xff) << (8 * b);
    }
    ws[t] = p;
  }
}

// relu-quant (scale 0.25, 0..15) then requant to next 4-bit input code (0..7),
// applied AFTER integer max-pooling (quant fns are monotone => commutes).
__device__ __forceinline__ int relu_requant(int acc_x2 /* value = acc*0.125 */) {
  int r = iclamp((int)rintf((float)acc_x2 * 0.5f), 0, 15);
  int c = (int)rintf((float)r * 0.5f);
  return c > 7 ? 7 : c;
}

__global__ __launch_bounds__(256, 4) void fused_net(
    const float* __restrict__ x,   // (1024,3,32,32)
    const int*   __restrict__ wq,  // quantized weight codes (layout above)
    float* __restrict__ out)       // (1024,10)
{
  const int img = blockIdx.x;
  const int tid = threadIdx.x;

  // ping-pong LDS: stages alternate A->B->A->...
  __shared__ __align__(16) signed char bufA[8192];
  __shared__ __align__(16) signed char bufB[8192];
  __shared__ int s_red[256];
  // total 17.4 KB -> >=4 blocks/CU, whole 1024-block grid resident at once

  // ---- stage 0: input quant(8b) + 1x1 conv w0 + 4b quant -> bufA [3][1024] ----
  {
    const float* xim = x + (size_t)img * 3072;
    const int p4 = tid * 4;
    float4 v0 = *(const float4*)(xim + p4);
    float4 v1 = *(const float4*)(xim + 1024 + p4);
    float4 v2 = *(const float4*)(xim + 2048 + p4);
    int w[9];
#pragma unroll
    for (int i = 0; i < 9; i++) w[i] = wq[W0i + i];
#define Q8(v) iclamp((int)rintf((v) * 16.f), -128, 127)
    int a0[4] = {Q8(v0.x), Q8(v0.y), Q8(v0.z), Q8(v0.w)};
    int a1[4] = {Q8(v1.x), Q8(v1.y), Q8(v1.z), Q8(v1.w)};
    int a2[4] = {Q8(v2.x), Q8(v2.y), Q8(v2.z), Q8(v2.w)};
#undef Q8
#pragma unroll
    for (int o = 0; o < 3; o++) {
      int pk = 0;
#pragma unroll
      for (int j = 0; j < 4; j++) {
        int s = a0[j] * w[o * 3] + a1[j] * w[o * 3 + 1] + a2[j] * w[o * 3 + 2];
        int c = iclamp((int)rintf((float)s * 0.03125f), -8, 7);  // *2^-5
        pk |= (c & 0xff) << (8 * j);
      }
      ((int*)bufA)[o * 256 + tid] = pk;
    }
  }
  __syncthreads();

  // ---- stage 1b: depthwise 3x3, 3ch 32x32 -> bufB [3][1024] (signed 4b) ----
  for (int it = 0; it < 12; it++) {
    int idx = tid + 256 * it;
    int c = it >> 2;                // wave-uniform -> weights in SGPRs
    int pos = idx & 1023;
    int y = pos >> 5, xx = pos & 31;
    int wk[9];
#pragma unroll
    for (int j = 0; j < 9; j++) wk[j] = (wq[DW1i + c * 9 + j] << 24) >> 24;
    const signed char* in = bufA + c * 1024;
    int acc = 0;
#pragma unroll
    for (int ky = 0; ky < 3; ky++) {
      int yy = y + ky - 1;
      if (yy < 0 || yy > 31) continue;
#pragma unroll
      for (int kx = 0; kx < 3; kx++) {
        int x2 = xx + kx - 1;
        if (x2 < 0 || x2 > 31) continue;
        acc += (int)in[yy * 32 + x2] * wk[ky * 3 + kx];
      }
    }
    bufB[c * 1024 + pos] =
        (signed char)iclamp((int)rintf((float)acc * 0.25f), -8, 7);
  }
  __syncthreads();

  // ---- stage 1c: pw1 (3->32) + relu-q + pool2 + requant -> bufA [256pos][32ch]
  // pos==tid for all iterations -> the 12 input bytes are loop-invariant.
  {
    int py = tid >> 4, px = tid & 15;
    int a[4][3];
#pragma unroll
    for (int d = 0; d < 4; d++) {
      int sp = (2 * py + (d >> 1)) * 32 + 2 * px + (d & 1);
#pragma unroll
      for (int c = 0; c < 3; c++) a[d][c] = bufB[c * 1024 + sp];
    }
    for (int it = 0; it < 8; it++) {     // channel quad, wave-uniform
      int pk = 0;
#pragma unroll
      for (int j = 0; j < 4; j++) {
        int o = it * 4 + j;
        int wA = (wq[PW1i + o * 3    ] << 24) >> 24;
        int wB = (wq[PW1i + o * 3 + 1] << 24) >> 24;
        int wC = (wq[PW1i + o * 3 + 2] << 24) >> 24;
        int mx = -1000000;
#pragma unroll
        for (int d = 0; d < 4; d++) {
          int acc = a[d][0] * wA + a[d][1] * wB + a[d][2] * wC;
          mx = mx > acc ? mx : acc;
        }
        pk |= relu_requant(mx) << (8 * j);   // codes 0..7
      }
      ((int*)bufA)[tid * 8 + it] = pk;
    }
  }
  __syncthreads();

  // ---- stage 2a: depthwise 3x3, 32ch 16x16 -> bufB [256pos][32ch] signed ----
  {
    int y = tid >> 4, xx = tid & 15;
    for (int it = 0; it < 8; it++) {     // channel quad, wave-uniform
      int wk[9][4];
#pragma unroll
      for (int j = 0; j < 9; j++)
#pragma unroll
        for (int cc = 0; cc < 4; cc++)
          wk[j][cc] = (wq[DW2i + (it * 4 + cc) * 9 + j] << 24) >> 24;
      int acc[4] = {0, 0, 0, 0};
#pragma unroll
      for (int ky = 0; ky < 3; ky++) {
        int yy = y + ky - 1;
        if (yy < 0 || yy > 15) continue;
#pragma unroll
        for (int kx = 0; kx < 3; kx++) {
          int x2 = xx + kx - 1;
          if (x2 < 0 || x2 > 15) continue;
          int d = ((const int*)bufA)[(yy * 16 + x2) * 8 + it];
#pragma unroll
          for (int cc = 0; cc < 4; cc++)
            acc[cc] += ((d >> (8 * cc)) & 0xff) * wk[ky * 3 + kx][cc];
        }
      }
      int pk = 0;
#pragma unroll
      for (int cc = 0; cc < 4; cc++) {
        int c = iclamp((int)rintf((float)acc[cc] * 0.25f), -8, 7);
        pk |= (c & 0xff) << (8 * cc);
      }
      ((int*)bufB)[tid * 8 + it] = pk;
    }
  }
  __syncthreads();

  // ---- stage 2b: pw2 (32->64, sdot4) + relu-q + pool2 + requant
  //      bufB [256][32] -> bufA [64pos][64ch] (codes 0..7) ----
  {
    int oq = tid & 15;                  // output-channel quad (o = oq*4+j)
    int4 w4[4][2];
#pragma unroll
    for (int j = 0; j < 4; j++) {
      const int4* wp = (const int4*)(wq + PW2p + (oq * 4 + j) * 8);
      w4[j][0] = wp[0]; w4[j][1] = wp[1];
    }
    for (int it = 0; it < 4; it++) {
      int pp = (tid >> 4) + 16 * it;    // pooled position 0..63
      int py = pp >> 3, px = pp & 7;
      int mx[4] = {-1000000, -1000000, -1000000, -1000000};
#pragma unroll
      for (int d = 0; d < 4; d++) {
        int sp = (2 * py + (d >> 1)) * 16 + 2 * px + (d & 1);
        const int4* ap = (const int4*)(bufB + sp * 32);
        int4 A0 = ap[0], A1 = ap[1];
#pragma unroll
        for (int j = 0; j < 4; j++) {
          int acc = dot4(A0.x, w4[j][0].x, 0);
          acc = dot4(A0.y, w4[j][0].y, acc);
          acc = dot4(A0.z, w4[j][0].z, acc);
          acc = dot4(A0.w, w4[j][0].w, acc);
          acc = dot4(A1.x, w4[j][1].x, acc);
          acc = dot4(A1.y, w4[j][1].y, acc);
          acc = dot4(A1.z, w4[j][1].z, acc);
          acc = dot4(A1.w, w4[j][1].w, acc);
          mx[j] = mx[j] > acc ? mx[j] : acc;
        }
      }
      int pk = 0;
#pragma unroll
      for (int j = 0; j < 4; j++) pk |= relu_requant(mx[j]) << (8 * j);
      ((int*)bufA)[pp * 16 + oq] = pk;
    }
  }
  __syncthreads();

  // ---- stage 3a: depthwise 3x3, 64ch 8x8 -> bufB [64pos][64ch] signed ----
  {
    int pos = tid & 63;
    int y = pos >> 3, xx = pos & 7;
    int sub = tid >> 6;                 // 0..3, wave-uniform
    for (int it = 0; it < 4; it++) {
      int cq = sub + 4 * it;            // 0..15, wave-uniform
      int wk[9][4];
#pragma unroll
      for (int j = 0; j < 9; j++)
#pragma unroll
        for (int cc = 0; cc < 4; cc++)
          wk[j][cc] = (wq[DW3i + (cq * 4 + cc) * 9 + j] << 24) >> 24;
      int acc[4] = {0, 0, 0, 0};
#pragma unroll
      for (int ky = 0; ky < 3; ky++) {
        int yy = y + ky - 1;
        if (yy < 0 || yy > 7) continue;
#pragma unroll
        for (int kx = 0; kx < 3; kx++) {
          int x2 = xx + kx - 1;
          if (x2 < 0 || x2 > 7) continue;
          int d = ((const int*)bufA)[(yy * 8 + x2) * 16 + cq];
#pragma unroll
          for (int cc = 0; cc < 4; cc++)
            acc[cc] += ((d >> (8 * cc)) & 0xff) * wk[ky * 3 + kx][cc];
        }
      }
      int pk = 0;
#pragma unroll
      for (int cc = 0; cc < 4; cc++) {
        int c = iclamp((int)rintf((float)acc[cc] * 0.25f), -8, 7);
        pk |= (c & 0xff) << (8 * cc);
      }
      ((int*)bufB)[pos * 16 + cq] = pk;
    }
  }
  __syncthreads();

  // ---- stage 3b: pw3 (64->128, sdot4) + global max pool ----
  {
    int o = tid >> 1, half = tid & 1;
    const int4* wp = (const int4*)(wq + PW3p + o * 16);
    int4 w0v = wp[0], w1v = wp[1], w2v = wp[2], w3v = wp[3];
    int mx = -1000000;
    for (int k = 0; k < 32; k++) {
      int sp = half + 2 * k;
      const int4* ap = (const int4*)(bufB + sp * 64);
      int4 A0 = ap[0], A1 = ap[1], A2 = ap[2], A3 = ap[3];
      int acc = dot4(A0.x, w0v.x, 0);
      acc = dot4(A0.y, w0v.y, acc); acc = dot4(A0.z, w0v.z, acc);
      acc = dot4(A0.w, w0v.w, acc);
      acc = dot4(A1.x, w1v.x, acc); acc = dot4(A1.y, w1v.y, acc);
      acc = dot4(A1.z, w1v.z, acc); acc = dot4(A1.w, w1v.w, acc);
      acc = dot4(A2.x, w2v.x, acc); acc = dot4(A2.y, w2v.y, acc);
      acc = dot4(A2.z, w2v.z, acc); acc = dot4(A2.w, w2v.w, acc);
      acc = dot4(A3.x, w3v.x, acc); acc = dot4(A3.y, w3v.y, acc);
      acc = dot4(A3.z, w3v.z, acc); acc = dot4(A3.w, w3v.w, acc);
      mx = mx > acc ? mx : acc;
    }
    s_red[tid] = mx;
  }
  __syncthreads();
  if (tid < 128) {
    int mm = s_red[2 * tid] > s_red[2 * tid + 1] ? s_red[2 * tid]
                                                 : s_red[2 * tid + 1];
    bufA[tid] = (signed char)relu_requant(mm);   // fc1 input codes 0..7
  }
  __syncthreads();

  // ---- fc1: 128 -> 256 (sdot4) -> bufB[0..255] codes 0..7 ----
  {
    const int4* wp = (const int4*)(wq + WC1p + tid * 32);
    const int4* mp = (const int4*)bufA;
    int acc = 0;
#pragma unroll
    for (int rI = 0; rI < 8; rI++) {
      int4 a = mp[rI]; int4 w = wp[rI];
      acc = dot4(a.x, w.x, acc); acc = dot4(a.y, w.y, acc);
      acc = dot4(a.z, w.z, acc); acc = dot4(a.w, w.w, acc);
    }
    bufB[tid] = (signed char)relu_requant(acc);
  }
  __syncthreads();

  // ---- fc2: 256 -> 10 + int8 output quant ----
  if (tid < 80) {
    int k = tid >> 3, j = tid & 7;
    const int4* wp = (const int4*)(wq + WC2p + k * 64 + j * 8);
    int4 w0v = wp[0], w1v = wp[1];
    const int4* ap = (const int4*)bufB;
    int4 A0 = ap[j * 2], A1 = ap[j * 2 + 1];
    int acc = dot4(A0.x, w0v.x, 0);
    acc = dot4(A0.y, w0v.y, acc); acc = dot4(A0.z, w0v.z, acc);
    acc = dot4(A0.w, w0v.w, acc);
    acc = dot4(A1.x, w1v.x, acc); acc = dot4(A1.y, w1v.y, acc);
    acc = dot4(A1.z, w1v.z, acc); acc = dot4(A1.w, w1v.w, acc);
    s_red[tid] = acc;
  }
  __syncthreads();
  if (tid < 10) {
    int acc = 0;
#pragma unroll
    for (int j = 0; j < 8; j++) acc += s_red[tid * 8 + j];
    // value = acc*0.125; fq_signed(v, 2^-4, 8b): round(v*16) = 2*acc exactly
    int code = iclamp(2 * acc, -128, 127);
    out[(size_t)img * 10 + tid] = (float)code * 0.0625f;
  }
}

extern "C" void kernel_launch(void* const* d_in, const int* in_sizes, int n_in,
                              void* d_out, int out_size, void* d_ws, size_t ws_size,
                              hipStream_t stream) {
  const float* x   = (const float*)d_in[0];
  const float* w0  = (const float*)d_in[1];
  const float* dw1 = (const float*)d_in[2];
  const float* pw1 = (const float*)d_in[3];
  const float* dw2 = (const float*)d_in[4];
  const float* pw2 = (const float*)d_in[5];
  const float* dw3 = (const float*)d_in[6];
  const float* pw3 = (const float*)d_in[7];
  const float* wc1 = (const float*)d_in[8];
  const float* wc2 = (const float*)d_in[9];
  int*   wsq = (int*)d_ws;     // 12388 ints = 49.5 KB (L2-resident)
  float* out = (float*)d_out;  // (1024,10,1,1) fp32

  prep_weights<<<(WTOT + 255) / 256, 256, 0, stream>>>(
      w0, dw1, pw1, dw2, pw2, dw3, pw3, wc1, wc2, wsq);
  fused_net<<<1024, 256, 0, stream>>>(x, wsq, out);
}

// Round 3
// 105.926 us; speedup vs baseline: 2.8427x; 1.1089x over previous
//
#include <hip/hip_runtime.h>

// ---- weight workspace layout (int32 units) ---- (unchanged from R2)
#define W0i   0       // 9   int codes (8-bit, -128..127)
#define DW1i  9       // 27  int codes (4-bit)
#define PW1i  36      // 96  int codes
#define DW2i  132     // 288 int codes
#define DW3i  420     // 576 int codes
#define PW2p  996     // 512  packed i8x4: [o=0..63][k4=0..7]
#define PW3p  1508    // 2048 packed:     [o=0..127][k4=0..15]
#define WC1p  3556    // 8192 packed:     [o=0..255][k4=0..31]
#define WC2p  11748   // 640  packed:     [o=0..9][k4=0..63]
#define WTOT  12388

__device__ __forceinline__ int iclamp(int v, int lo, int hi) {
  return v < lo ? lo : (v > hi ? hi : v);
}

// round-half-even of a/4 (exact match to jnp.round semantics on .25/.5/.75)
__device__ __forceinline__ int rne4(int a) {
  return (a + 1 + ((a >> 2) & 1)) >> 2;
}
// round-half-even of a/32
__device__ __forceinline__ int rne32(int a) {
  return (a + 15 + ((a >> 5) & 1)) >> 5;
}

__device__ __forceinline__ int dot4(int a, int b, int c) {
#if defined(__has_builtin)
#if __has_builtin(__builtin_amdgcn_sdot4)
  return __builtin_amdgcn_sdot4(a, b, c, false);
#else
  c += ((a << 24) >> 24) * ((b << 24) >> 24);
  c += ((a << 16) >> 24) * ((b << 16) >> 24);
  c += ((a <<  8) >> 24) * ((b <<  8) >> 24);
  c += (a >> 24) * (b >> 24);
  return c;
#endif
#else
  c += ((a << 24) >> 24) * ((b << 24) >> 24);
  c += ((a << 16) >> 24) * ((b << 16) >> 24);
  c += ((a <<  8) >> 24) * ((b <<  8) >> 24);
  c += (a >> 24) * (b >> 24);
  return c;
#endif
}

// byte-sliding window: result = ((hi:lo) >> 8*sh) & 0xffffffff
__device__ __forceinline__ int alignb(int hi, int lo, int sh) {
#if defined(__has_builtin)
#if __has_builtin(__builtin_amdgcn_alignbyte)
  return __builtin_amdgcn_alignbyte(hi, lo, sh);
#else
  return (int)(((((unsigned long long)(unsigned)hi) << 32) |
                (unsigned)lo) >> (8 * sh));
#endif
#else
  return (int)(((((unsigned long long)(unsigned)hi) << 32) |
                (unsigned)lo) >> (8 * sh));
#endif
}

__device__ __forceinline__ int pack3(int a, int b, int c) {
  return (a & 0xff) | ((b & 0xff) << 8) | ((c & 0xff) << 16);
}

__global__ __launch_bounds__(256) void prep_weights(
    const float* __restrict__ w0,  const float* __restrict__ dw1,
    const float* __restrict__ pw1, const float* __restrict__ dw2,
    const float* __restrict__ pw2, const float* __restrict__ dw3,
    const float* __restrict__ pw3, const float* __restrict__ wc1,
    const float* __restrict__ wc2, int* __restrict__ ws) {
  int t = blockIdx.x * blockDim.x + threadIdx.x;
  if (t >= WTOT) return;
  if (t < PW2p) {
    float w; int lo = -8, hi = 7;
    if (t < DW1i)      { w = w0[t];        lo = -128; hi = 127; }
    else if (t < PW1i)   w = dw1[t - DW1i];
    else if (t < DW2i)   w = pw1[t - PW1i];
    else if (t < DW3i)   w = dw2[t - DW2i];
    else                 w = dw3[t - DW3i];
    ws[t] = iclamp((int)rintf(w * 4.f), lo, hi);   // code = round(w / 0.25)
  } else {
    const float* src;
    if (t < WC1p) {
      if (t < PW3p) src = pw2 + (t - PW2p) * 4;
      else          src = pw3 + (t - PW3p) * 4;
    } else {
      if (t < WC2p) src = wc1 + (t - WC1p) * 4;
      else          src = wc2 + (t - WC2p) * 4;
    }
    int p = 0;
#pragma unroll
    for (int b = 0; b < 4; b++) {
      int c = iclamp((int)rintf(src[b] * 4.f), -8, 7);
      p |= (c & 0xff) << (8 * b);
    }
    ws[t] = p;
  }
}

// Conflict-free LDS layouts (all strides co-prime-ish with 32 banks):
//  A0: [c][256]              dword = c*256 + t             (stage0 -> 1b)
//  B0: [c][256]              dword = c*256 + strip         (1b -> 1c)
//  A1: dword = y*149 + x*9  + cq   (16x16, 8 ch-quads)     (1c -> 2a)
//  B1: dword = y*162 + x*10 + cq   (16x16, 8 quads, int2-aligned)  (2a -> 2b)
//  A2: dword = py*137 + px*17 + oq (8x8, 16 quads)         (2b -> 3a)
//  B2: dword = y*164 + x*20 + cq2  (8x8, 16 quads, b128-aligned)   (3a -> 3b)
__global__ __launch_bounds__(256, 4) void fused_net(
    const float* __restrict__ x,   // (1024,3,32,32)
    const int*   __restrict__ wq,  // quantized weight codes (layout above)
    float* __restrict__ out)       // (1024,10)
{
  const int img = blockIdx.x;
  const int tid = threadIdx.x;

  __shared__ __align__(16) int bufAi[2384];
  __shared__ __align__(16) int bufBi[2592];
  __shared__ int s_red[256];
  // 20928 B total

  // ---- stage 0: input quant(8b) + 1x1 conv w0 + 4b quant -> A0 ----
  {
    const float* xim = x + (size_t)img * 3072;
    const int p4 = tid * 4;
    float4 v0 = *(const float4*)(xim + p4);
    float4 v1 = *(const float4*)(xim + 1024 + p4);
    float4 v2 = *(const float4*)(xim + 2048 + p4);
    int w[9];
#pragma unroll
    for (int i = 0; i < 9; i++) w[i] = wq[W0i + i];
#define Q8(v) iclamp((int)rintf((v) * 16.f), -128, 127)
    int a0[4] = {Q8(v0.x), Q8(v0.y), Q8(v0.z), Q8(v0.w)};
    int a1[4] = {Q8(v1.x), Q8(v1.y), Q8(v1.z), Q8(v1.w)};
    int a2[4] = {Q8(v2.x), Q8(v2.y), Q8(v2.z), Q8(v2.w)};
#undef Q8
#pragma unroll
    for (int o = 0; o < 3; o++) {
      int pk = 0;
#pragma unroll
      for (int j = 0; j < 4; j++) {
        int s = a0[j] * w[o * 3] + a1[j] * w[o * 3 + 1] + a2[j] * w[o * 3 + 2];
        pk |= (iclamp(rne32(s), -8, 7) & 0xff) << (8 * j);
      }
      bufAi[o * 256 + tid] = pk;
    }
  }
  __syncthreads();

  // ---- stage 1b: dw 3x3, 3ch 32x32 (strip of 4 via alignbyte+sdot4) -> B0 ----
  {
    const int y = tid >> 3, q = tid & 7;
#pragma unroll
    for (int c = 0; c < 3; c++) {
      int wr[3];
#pragma unroll
      for (int r = 0; r < 3; r++)
        wr[r] = pack3(wq[DW1i + c * 9 + r * 3], wq[DW1i + c * 9 + r * 3 + 1],
                      wq[DW1i + c * 9 + r * 3 + 2]);
      const int* ap = bufAi + c * 256;
      int acc0 = 0, acc1 = 0, acc2 = 0, acc3 = 0;
#pragma unroll
      for (int ky = 0; ky < 3; ky++) {
        int yy = y + ky - 1;
        if (yy < 0 || yy > 31) continue;
        int base = yy * 8 + q;
        int dC = ap[base];
        int dL = q ? ap[base - 1] : 0;
        int dR = (q < 7) ? ap[base + 1] : 0;
        int w = wr[ky];
        acc0 = dot4(alignb(dC, dL, 3), w, acc0);
        acc1 = dot4(dC, w, acc1);
        acc2 = dot4(alignb(dR, dC, 1), w, acc2);
        acc3 = dot4(alignb(dR, dC, 2), w, acc3);
      }
      int pk = (iclamp(rne4(acc0), -8, 7) & 0xff) |
               ((iclamp(rne4(acc1), -8, 7) & 0xff) << 8) |
               ((iclamp(rne4(acc2), -8, 7) & 0xff) << 16) |
               ((iclamp(rne4(acc3), -8, 7) & 0xff) << 24);
      bufBi[c * 256 + tid] = pk;
    }
  }
  __syncthreads();

  // ---- stage 1c: pw1 (3->32, sdot4) + relu-q + pool2 + requant -> A1 ----
  {
    const int py = tid >> 4, px = tid & 15;
    const signed char* bB = (const signed char*)bufBi;
    int a[4];
#pragma unroll
    for (int d = 0; d < 4; d++) {
      int sp = (2 * py + (d >> 1)) * 32 + 2 * px + (d & 1);
      a[d] = pack3(bB[sp], bB[1024 + sp], bB[2048 + sp]);
    }
#pragma unroll
    for (int it = 0; it < 8; it++) {
      int pk = 0;
#pragma unroll
      for (int j = 0; j < 4; j++) {
        int o = it * 4 + j;
        int wpk = pack3(wq[PW1i + o * 3], wq[PW1i + o * 3 + 1],
                        wq[PW1i + o * 3 + 2]);
        int m0 = dot4(a[0], wpk, 0), m1 = dot4(a[1], wpk, 0);
        int m2 = dot4(a[2], wpk, 0), m3 = dot4(a[3], wpk, 0);
        int mx = max(max(m0, m1), max(m2, m3));
        pk |= iclamp(rne4(mx), 0, 7) << (8 * j);
      }
      bufAi[py * 149 + px * 9 + it] = pk;
    }
  }
  __syncthreads();

  // ---- stage 2a: dw 3x3, 32ch 16x16 (strip of 4) A1 -> B1 ----
  for (int it2 = 0; it2 < 2; it2++) {
    int idx = tid + 256 * it2;
    int cq = __builtin_amdgcn_readfirstlane(idx >> 6);   // wave-uniform
    int s = idx & 63;
    int y = s >> 2, x0 = (s & 3) << 2;
    int wk[9][4];
#pragma unroll
    for (int t9 = 0; t9 < 9; t9++)
#pragma unroll
      for (int cc = 0; cc < 4; cc++)
        wk[t9][cc] = wq[DW2i + (cq * 4 + cc) * 9 + t9];
    int acc[4][4] = {};
#pragma unroll
    for (int ky = 0; ky < 3; ky++) {
      int yy = y + ky - 1;
      if (yy < 0 || yy > 15) continue;
      int rb = yy * 149 + cq;
      int rd[6];
      rd[0] = (x0 > 0) ? bufAi[rb + (x0 - 1) * 9] : 0;
      rd[1] = bufAi[rb + x0 * 9];
      rd[2] = bufAi[rb + (x0 + 1) * 9];
      rd[3] = bufAi[rb + (x0 + 2) * 9];
      rd[4] = bufAi[rb + (x0 + 3) * 9];
      rd[5] = (x0 < 12) ? bufAi[rb + (x0 + 4) * 9] : 0;
      int e[6][4];
#pragma unroll
      for (int k = 0; k < 6; k++)
#pragma unroll
        for (int cc = 0; cc < 4; cc++) e[k][cc] = (rd[k] >> (8 * cc)) & 0xf;
#pragma unroll
      for (int j = 0; j < 4; j++)
#pragma unroll
        for (int kx = 0; kx < 3; kx++)
#pragma unroll
          for (int cc = 0; cc < 4; cc++)
            acc[j][cc] += e[j + kx][cc] * wk[ky * 3 + kx][cc];
    }
#pragma unroll
    for (int j = 0; j < 4; j++) {
      int pk = 0;
#pragma unroll
      for (int cc = 0; cc < 4; cc++)
        pk |= (iclamp(rne4(acc[j][cc]), -8, 7) & 0xff) << (8 * cc);
      bufBi[y * 162 + (x0 + j) * 10 + cq] = pk;
    }
  }
  __syncthreads();

  // ---- stage 2b: pw2 (32->64, sdot4) + relu-q + pool2 + requant B1 -> A2 ----
  {
    int oq = tid & 15;
    int4 w4[4][2];
#pragma unroll
    for (int j = 0; j < 4; j++) {
      const int4* wp = (const int4*)(wq + PW2p + (oq * 4 + j) * 8);
      w4[j][0] = wp[0]; w4[j][1] = wp[1];
    }
    for (int it = 0; it < 4; it++) {
      int pp = (tid >> 4) + 16 * it;
      int py = pp >> 3, px = pp & 7;
      int mx[4] = {-1000000, -1000000, -1000000, -1000000};
#pragma unroll
      for (int d = 0; d < 4; d++) {
        int sy = 2 * py + (d >> 1), sx = 2 * px + (d & 1);
        const int2* ap = (const int2*)(bufBi + sy * 162 + sx * 10);
        int2 A0 = ap[0], A1 = ap[1], A2 = ap[2], A3 = ap[3];
#pragma unroll
        for (int j = 0; j < 4; j++) {
          int acc = dot4(A0.x, w4[j][0].x, 0);
          acc = dot4(A0.y, w4[j][0].y, acc);
          acc = dot4(A1.x, w4[j][0].z, acc);
          acc = dot4(A1.y, w4[j][0].w, acc);
          acc = dot4(A2.x, w4[j][1].x, acc);
          acc = dot4(A2.y, w4[j][1].y, acc);
          acc = dot4(A3.x, w4[j][1].z, acc);
          acc = dot4(A3.y, w4[j][1].w, acc);
          mx[j] = mx[j] > acc ? mx[j] : acc;
        }
      }
      int pk = 0;
#pragma unroll
      for (int j = 0; j < 4; j++)
        pk |= iclamp(rne4(mx[j]), 0, 7) << (8 * j);
      bufAi[py * 137 + px * 17 + oq] = pk;
    }
  }
  __syncthreads();

  // ---- stage 3a: dw 3x3, 64ch 8x8 (strip of 4) A2 -> B2 ----
  {
    int cq2 = tid >> 4;                 // 0..15 (varies within wave; VMEM weights)
    int s = tid & 15;
    int y = s >> 1, x0 = (s & 1) << 2;
    int wk[9][4];
#pragma unroll
    for (int t9 = 0; t9 < 9; t9++)
#pragma unroll
      for (int cc = 0; cc < 4; cc++)
        wk[t9][cc] = wq[DW3i + (cq2 * 4 + cc) * 9 + t9];
    int acc[4][4] = {};
#pragma unroll
    for (int ky = 0; ky < 3; ky++) {
      int yy = y + ky - 1;
      if (yy < 0 || yy > 7) continue;
      int rb = yy * 137 + cq2;
      int rd[6];
      rd[0] = (x0 == 4) ? bufAi[rb + (x0 - 1) * 17] : 0;
      rd[1] = bufAi[rb + x0 * 17];
      rd[2] = bufAi[rb + (x0 + 1) * 17];
      rd[3] = bufAi[rb + (x0 + 2) * 17];
      rd[4] = bufAi[rb + (x0 + 3) * 17];
      rd[5] = (x0 == 0) ? bufAi[rb + (x0 + 4) * 17] : 0;
      int e[6][4];
#pragma unroll
      for (int k = 0; k < 6; k++)
#pragma unroll
        for (int cc = 0; cc < 4; cc++) e[k][cc] = (rd[k] >> (8 * cc)) & 0xf;
#pragma unroll
      for (int j = 0; j < 4; j++)
#pragma unroll
        for (int kx = 0; kx < 3; kx++)
#pragma unroll
          for (int cc = 0; cc < 4; cc++)
            acc[j][cc] += e[j + kx][cc] * wk[ky * 3 + kx][cc];
    }
#pragma unroll
    for (int j = 0; j < 4; j++) {
      int pk = 0;
#pragma unroll
      for (int cc = 0; cc < 4; cc++)
        pk |= (iclamp(rne4(acc[j][cc]), -8, 7) & 0xff) << (8 * cc);
      bufBi[y * 164 + (x0 + j) * 20 + cq2] = pk;
    }
  }
  __syncthreads();

  // ---- stage 3b: pw3 (64->128, sdot4) + global max pool B2 -> s_red ----
  {
    int o = tid >> 1, half = tid & 1;
    const int4* wp = (const int4*)(wq + PW3p + o * 16);
    int4 w0v = wp[0], w1v = wp[1], w2v = wp[2], w3v = wp[3];
    int mx = -1000000;
    for (int k = 0; k < 32; k++) {
      int sp = half + 2 * k;
      int py = sp >> 3, px = sp & 7;
      const int4* ap = (const int4*)(bufBi + py * 164 + px * 20);
      int4 A0 = ap[0], A1 = ap[1], A2 = ap[2], A3 = ap[3];
      int acc = dot4(A0.x, w0v.x, 0);
      acc = dot4(A0.y, w0v.y, acc); acc = dot4(A0.z, w0v.z, acc);
      acc = dot4(A0.w, w0v.w, acc);
      acc = dot4(A1.x, w1v.x, acc); acc = dot4(A1.y, w1v.y, acc);
      acc = dot4(A1.z, w1v.z, acc); acc = dot4(A1.w, w1v.w, acc);
      acc = dot4(A2.x, w2v.x, acc); acc = dot4(A2.y, w2v.y, acc);
      acc = dot4(A2.z, w2v.z, acc); acc = dot4(A2.w, w2v.w, acc);
      acc = dot4(A3.x, w3v.x, acc); acc = dot4(A3.y, w3v.y, acc);
      acc = dot4(A3.z, w3v.z, acc); acc = dot4(A3.w, w3v.w, acc);
      mx = mx > acc ? mx : acc;
    }
    s_red[tid] = mx;
  }
  __syncthreads();
  if (tid < 128) {
    int mm = s_red[2 * tid] > s_red[2 * tid + 1] ? s_red[2 * tid]
                                                 : s_red[2 * tid + 1];
    ((signed char*)bufAi)[tid] = (signed char)iclamp(rne4(mm), 0, 7);
  }
  __syncthreads();

  // ---- fc1: 128 -> 256 (sdot4) -> bufB bytes 0..255 ----
  {
    const int4* wp = (const int4*)(wq + WC1p + tid * 32);
    const int4* mp = (const int4*)bufAi;
    int acc = 0;
#pragma unroll
    for (int rI = 0; rI < 8; rI++) {
      int4 a = mp[rI]; int4 w = wp[rI];
      acc = dot4(a.x, w.x, acc); acc = dot4(a.y, w.y, acc);
      acc = dot4(a.z, w.z, acc); acc = dot4(a.w, w.w, acc);
    }
    ((signed char*)bufBi)[tid] = (signed char)iclamp(rne4(acc), 0, 7);
  }
  __syncthreads();

  // ---- fc2: 256 -> 10 + int8 output quant ----
  if (tid < 80) {
    int k = tid >> 3, j = tid & 7;
    const int4* wp = (const int4*)(wq + WC2p + k * 64 + j * 8);
    int4 w0v = wp[0], w1v = wp[1];
    const int4* ap = (const int4*)bufBi;
    int4 A0 = ap[j * 2], A1 = ap[j * 2 + 1];
    int acc = dot4(A0.x, w0v.x, 0);
    acc = dot4(A0.y, w0v.y, acc); acc = dot4(A0.z, w0v.z, acc);
    acc = dot4(A0.w, w0v.w, acc);
    acc = dot4(A1.x, w1v.x, acc); acc = dot4(A1.y, w1v.y, acc);
    acc = dot4(A1.z, w1v.z, acc); acc = dot4(A1.w, w1v.w, acc);
    s_red[tid] = acc;
  }
  __syncthreads();
  if (tid < 10) {
    int acc = 0;
#pragma unroll
    for (int j = 0; j < 8; j++) acc += s_red[tid * 8 + j];
    // value = acc*0.125; fq_signed(v, 2^-4, 8b): round(v*16) = 2*acc exactly
    int code = iclamp(2 * acc, -128, 127);
    out[(size_t)img * 10 + tid] = (float)code * 0.0625f;
  }
}

extern "C" void kernel_launch(void* const* d_in, const int* in_sizes, int n_in,
                              void* d_out, int out_size, void* d_ws, size_t ws_size,
                              hipStream_t stream) {
  const float* x   = (const float*)d_in[0];
  const float* w0  = (const float*)d_in[1];
  const float* dw1 = (const float*)d_in[2];
  const float* pw1 = (const float*)d_in[3];
  const float* dw2 = (const float*)d_in[4];
  const float* pw2 = (const float*)d_in[5];
  const float* dw3 = (const float*)d_in[6];
  const float* pw3 = (const float*)d_in[7];
  const float* wc1 = (const float*)d_in[8];
  const float* wc2 = (const float*)d_in[9];
  int*   wsq = (int*)d_ws;     // 12388 ints = 49.5 KB (L2-resident)
  float* out = (float*)d_out;  // (1024,10,1,1) fp32

  prep_weights<<<(WTOT + 255) / 256, 256, 0, stream>>>(
      w0, dw1, pw1, dw2, pw2, dw3, pw3, wc1, wc2, wsq);
  fused_net<<<1024, 256, 0, stream>>>(x, wsq, out);
}

// Round 4
// 97.878 us; speedup vs baseline: 3.0764x; 1.0822x over previous
//
#include <hip/hip_runtime.h>

typedef int v4i __attribute__((ext_vector_type(4)));

// ---- weight workspace layout (int32 units) ----
#define W0i   0       // 9   int codes (8-bit, -128..127)
#define DW1i  9       // 27  int codes (4-bit)
#define PW1i  36      // 96  int codes
#define DW2i  132     // 288 int codes
#define DW3i  420     // 576 int codes
#define PW2p  996     // 512  packed i8x4 (legacy, unused by fused_net)
#define PW3p  1508    // 2048 packed (legacy, unused)
#define WC1p  3556    // 8192 packed:  [o=0..255][k4=0..31]
#define WC2p  11748   // 640  packed:  [o=0..9][k4=0..63]
#define PW2Fb 12388   // 512  dwords: pw2 B-frags [nt(4)][lane(64)][dw(2)]
#define PW3Fb 12900   // 2048 dwords: pw3 B-frags [nt(8)*2+kh][lane(64)][dw(2)]
#define WTOT  14948

__device__ __forceinline__ int iclamp(int v, int lo, int hi) {
  return v < lo ? lo : (v > hi ? hi : v);
}
// round-half-even of a/4 and a/32 (exact jnp.round semantics, all-integer)
__device__ __forceinline__ int rne4(int a) {
  return (a + 1 + ((a >> 2) & 1)) >> 2;
}
__device__ __forceinline__ int rne32(int a) {
  return (a + 15 + ((a >> 5) & 1)) >> 5;
}

__device__ __forceinline__ int dot4(int a, int b, int c) {
#if defined(__has_builtin) && __has_builtin(__builtin_amdgcn_sdot4)
  return __builtin_amdgcn_sdot4(a, b, c, false);
#else
  c += ((a << 24) >> 24) * ((b << 24) >> 24);
  c += ((a << 16) >> 24) * ((b << 16) >> 24);
  c += ((a <<  8) >> 24) * ((b <<  8) >> 24);
  c += (a >> 24) * (b >> 24);
  return c;
#endif
}

__device__ __forceinline__ int alignb(int hi, int lo, int sh) {
#if defined(__has_builtin) && __has_builtin(__builtin_amdgcn_alignbyte)
  return __builtin_amdgcn_alignbyte(hi, lo, sh);
#else
  return (int)(((((unsigned long long)(unsigned)hi) << 32) |
                (unsigned)lo) >> (8 * sh));
#endif
}

__device__ __forceinline__ int pack3(int a, int b, int c) {
  return (a & 0xff) | ((b & 0xff) << 8) | ((c & 0xff) << 16);
}

__global__ __launch_bounds__(256) void prep_weights(
    const float* __restrict__ w0,  const float* __restrict__ dw1,
    const float* __restrict__ pw1, const float* __restrict__ dw2,
    const float* __restrict__ pw2, const float* __restrict__ dw3,
    const float* __restrict__ pw3, const float* __restrict__ wc1,
    const float* __restrict__ wc2, int* __restrict__ ws) {
  int t = blockIdx.x * blockDim.x + threadIdx.x;
  if (t >= WTOT) return;
  if (t < PW2p) {
    float w; int lo = -8, hi = 7;
    if (t < DW1i)      { w = w0[t];        lo = -128; hi = 127; }
    else if (t < PW1i)   w = dw1[t - DW1i];
    else if (t < DW2i)   w = pw1[t - PW1i];
    else if (t < DW3i)   w = dw2[t - DW2i];
    else                 w = dw3[t - DW3i];
    ws[t] = iclamp((int)rintf(w * 4.f), lo, hi);
  } else if (t < PW2Fb) {
    const float* src;
    if (t < WC1p) {
      if (t < PW3p) src = pw2 + (t - PW2p) * 4;
      else          src = pw3 + (t - PW3p) * 4;
    } else {
      if (t < WC2p) src = wc1 + (t - WC1p) * 4;
      else          src = wc2 + (t - WC2p) * 4;
    }
    int p = 0;
#pragma unroll
    for (int b = 0; b < 4; b++) {
      int c = iclamp((int)rintf(src[b] * 4.f), -8, 7);
      p |= (c & 0xff) << (8 * b);
    }
    ws[t] = p;
  } else if (t < PW3Fb) {
    // pw2 MFMA B-fragment: B[k][n], n=nt*16+(lane&15), k=(lane>>4)*8+dw*4+b
    int i = t - PW2Fb;
    int nt = i >> 7, r = i & 127, lane = r >> 1, dw = r & 1;
    int n = nt * 16 + (lane & 15);
    int kb = (lane >> 4) * 8 + dw * 4;
    int p = 0;
#pragma unroll
    for (int b = 0; b < 4; b++) {
      int c = iclamp((int)rintf(pw2[n * 32 + kb + b] * 4.f), -8, 7);
      p |= (c & 0xff) << (8 * b);
    }
    ws[t] = p;
  } else {
    // pw3 MFMA B-fragment: k = kh*32 + (lane>>4)*8 + dw*4 + b
    int i = t - PW3Fb;
    int g = i >> 7, r = i & 127, lane = r >> 1, dw = r & 1;
    int nt = g >> 1, kh = g & 1;
    int n = nt * 16 + (lane & 15);
    int kb = kh * 32 + (lane >> 4) * 8 + dw * 4;
    int p = 0;
#pragma unroll
    for (int b = 0; b < 4; b++) {
      int c = iclamp((int)rintf(pw3[n * 64 + kb + b] * 4.f), -8, 7);
      p |= (c & 0xff) << (8 * b);
    }
    ws[t] = p;
  }
}

// LDS layouts:
//  A0:  [c][256] dwords                       (stage0 -> 1b)   bufA
//  B0:  [c][256] dwords                       (1b -> 1c)       bufB
//  A1:  dword = y*149 + x*9 + cq   (16x16)    (1c -> 2a)       bufA
//  B1:  dword = y*162 + x*10 + cq  (16x16)    (2a -> 2aT)      bufB
//  Apw2: MFMA A, byte = m*40 + k, m=qp*4+d, k=ch (K=32)        bufA
//  A2:  dword = py*137 + px*17 + oq (8x8)     (2b -> 3a)       bufB
//  Apw3: MFMA A, byte = pos*72 + k, k=ch (K=64)                bufA
//  fcin: bytes 0..127                          (3b -> fc1)     bufB
__global__ __launch_bounds__(256, 4) void fused_net(
    const float* __restrict__ x,   // (1024,3,32,32)
    const int*   __restrict__ wq,
    float* __restrict__ out)       // (1024,10)
{
  const int img = blockIdx.x;
  const int tid = threadIdx.x;

  __shared__ __align__(16) int bufAi[2560];
  __shared__ __align__(16) int bufBi[2592];
  __shared__ int s_red[256];
  // 21632 B -> 4 blocks/CU fits easily

  // ---- stage 0: input quant(8b) + 1x1 conv w0 + 4b quant -> A0 ----
  {
    const float* xim = x + (size_t)img * 3072;
    const int p4 = tid * 4;
    float4 v0 = *(const float4*)(xim + p4);
    float4 v1 = *(const float4*)(xim + 1024 + p4);
    float4 v2 = *(const float4*)(xim + 2048 + p4);
    int w[9];
#pragma unroll
    for (int i = 0; i < 9; i++) w[i] = wq[W0i + i];
#define Q8(v) iclamp((int)rintf((v) * 16.f), -128, 127)
    int a0[4] = {Q8(v0.x), Q8(v0.y), Q8(v0.z), Q8(v0.w)};
    int a1[4] = {Q8(v1.x), Q8(v1.y), Q8(v1.z), Q8(v1.w)};
    int a2[4] = {Q8(v2.x), Q8(v2.y), Q8(v2.z), Q8(v2.w)};
#undef Q8
#pragma unroll
    for (int o = 0; o < 3; o++) {
      int pk = 0;
#pragma unroll
      for (int j = 0; j < 4; j++) {
        int s = a0[j] * w[o * 3] + a1[j] * w[o * 3 + 1] + a2[j] * w[o * 3 + 2];
        pk |= (iclamp(rne32(s), -8, 7) & 0xff) << (8 * j);
      }
      bufAi[o * 256 + tid] = pk;
    }
  }
  __syncthreads();

  // ---- stage 1b: dw 3x3, 3ch 32x32 (strip of 4, alignbyte+sdot4) -> B0 ----
  {
    const int y = tid >> 3, q = tid & 7;
#pragma unroll
    for (int c = 0; c < 3; c++) {
      int wr[3];
#pragma unroll
      for (int r = 0; r < 3; r++)
        wr[r] = pack3(wq[DW1i + c * 9 + r * 3], wq[DW1i + c * 9 + r * 3 + 1],
                      wq[DW1i + c * 9 + r * 3 + 2]);
      const int* ap = bufAi + c * 256;
      int acc0 = 0, acc1 = 0, acc2 = 0, acc3 = 0;
#pragma unroll
      for (int ky = 0; ky < 3; ky++) {
        int yy = y + ky - 1;
        if (yy < 0 || yy > 31) continue;
        int base = yy * 8 + q;
        int dC = ap[base];
        int dL = q ? ap[base - 1] : 0;
        int dR = (q < 7) ? ap[base + 1] : 0;
        int w = wr[ky];
        acc0 = dot4(alignb(dC, dL, 3), w, acc0);
        acc1 = dot4(dC, w, acc1);
        acc2 = dot4(alignb(dR, dC, 1), w, acc2);
        acc3 = dot4(alignb(dR, dC, 2), w, acc3);
      }
      int pk = (iclamp(rne4(acc0), -8, 7) & 0xff) |
               ((iclamp(rne4(acc1), -8, 7) & 0xff) << 8) |
               ((iclamp(rne4(acc2), -8, 7) & 0xff) << 16) |
               ((iclamp(rne4(acc3), -8, 7) & 0xff) << 24);
      bufBi[c * 256 + tid] = pk;
    }
  }
  __syncthreads();

  // ---- stage 1c: pw1 (3->32, sdot4) + relu-q + pool2 + requant -> A1 ----
  {
    const int py = tid >> 4, px = tid & 15;
    const signed char* bB = (const signed char*)bufBi;
    int a[4];
#pragma unroll
    for (int d = 0; d < 4; d++) {
      int sp = (2 * py + (d >> 1)) * 32 + 2 * px + (d & 1);
      a[d] = pack3(bB[sp], bB[1024 + sp], bB[2048 + sp]);
    }
#pragma unroll
    for (int it = 0; it < 8; it++) {
      int pk = 0;
#pragma unroll
      for (int j = 0; j < 4; j++) {
        int o = it * 4 + j;
        int wpk = pack3(wq[PW1i + o * 3], wq[PW1i + o * 3 + 1],
                        wq[PW1i + o * 3 + 2]);
        int m0 = dot4(a[0], wpk, 0), m1 = dot4(a[1], wpk, 0);
        int m2 = dot4(a[2], wpk, 0), m3 = dot4(a[3], wpk, 0);
        int mx = max(max(m0, m1), max(m2, m3));
        pk |= iclamp(rne4(mx), 0, 7) << (8 * j);
      }
      bufAi[py * 149 + px * 9 + it] = pk;
    }
  }
  __syncthreads();

  // ---- stage 2a: dw 3x3, 32ch 16x16 (strip of 4) A1 -> B1 ----
  for (int it2 = 0; it2 < 2; it2++) {
    int idx = tid + 256 * it2;
    int cq = __builtin_amdgcn_readfirstlane(idx >> 6);   // wave-uniform
    int s = idx & 63;
    int y = s >> 2, x0 = (s & 3) << 2;
    int wk[9][4];
#pragma unroll
    for (int t9 = 0; t9 < 9; t9++)
#pragma unroll
      for (int cc = 0; cc < 4; cc++)
        wk[t9][cc] = wq[DW2i + (cq * 4 + cc) * 9 + t9];
    int acc[4][4] = {};
#pragma unroll
    for (int ky = 0; ky < 3; ky++) {
      int yy = y + ky - 1;
      if (yy < 0 || yy > 15) continue;
      int rb = yy * 149 + cq;
      int rd[6];
      rd[0] = (x0 > 0) ? bufAi[rb + (x0 - 1) * 9] : 0;
      rd[1] = bufAi[rb + x0 * 9];
      rd[2] = bufAi[rb + (x0 + 1) * 9];
      rd[3] = bufAi[rb + (x0 + 2) * 9];
      rd[4] = bufAi[rb + (x0 + 3) * 9];
      rd[5] = (x0 < 12) ? bufAi[rb + (x0 + 4) * 9] : 0;
      int e[6][4];
#pragma unroll
      for (int k = 0; k < 6; k++)
#pragma unroll
        for (int cc = 0; cc < 4; cc++) e[k][cc] = (rd[k] >> (8 * cc)) & 0xf;
#pragma unroll
      for (int j = 0; j < 4; j++)
#pragma unroll
        for (int kx = 0; kx < 3; kx++)
#pragma unroll
          for (int cc = 0; cc < 4; cc++)
            acc[j][cc] += e[j + kx][cc] * wk[ky * 3 + kx][cc];
    }
#pragma unroll
    for (int j = 0; j < 4; j++) {
      int pk = 0;
#pragma unroll
      for (int cc = 0; cc < 4; cc++)
        pk |= (iclamp(rne4(acc[j][cc]), -8, 7) & 0xff) << (8 * cc);
      bufBi[y * 162 + (x0 + j) * 10 + cq] = pk;
    }
  }
  __syncthreads();

  // ---- stage 2aT: transpose B1 -> Apw2 (MFMA A layout, pool-ordered m) ----
  // m = qp*4 + d  (qp = pooled pos, d = window elem); byte = m*40 + ch
#pragma unroll
  for (int i = 0; i < 4; i++) {
    int id = tid + 256 * i;
    int m = id >> 2, c2 = id & 3;
    int qp = m >> 2, d = m & 3;
    int sy = ((qp >> 3) << 1) + (d >> 1);
    int sx = ((qp & 7) << 1) + (d & 1);
    long v = *(const long*)(bufBi + sy * 162 + sx * 10 + c2 * 2);
    *(long*)(bufAi + m * 10 + c2 * 2) = v;
  }
  __syncthreads();

  // ---- stage 2b: pw2 via MFMA i32_16x16x32_i8, fused relu+pool2 -> A2 ----
  {
    const int w = tid >> 6, lane = tid & 63;
    const int lm = lane & 15, kg = lane >> 4;
    const long bw = *(const long*)(wq + PW2Fb + (w * 64 + lane) * 2);
    const signed char* Ab = (const signed char*)bufAi;
    signed char* A2c = (signed char*)bufBi;
    const int n = w * 16 + lm;
#pragma unroll 4
    for (int mt = 0; mt < 16; mt++) {
      int m = mt * 16 + lm;
      long av = *(const long*)(Ab + m * 40 + kg * 8);
      v4i d = __builtin_amdgcn_mfma_i32_16x16x32_i8(av, bw, (v4i){0, 0, 0, 0},
                                                    0, 0, 0);
      // lane's 4 accs = pool window of pooled pos qp = mt*4 + kg, channel n
      int mx = max(max(d[0], d[1]), max(d[2], d[3]));
      int qp = mt * 4 + kg;
      int py = qp >> 3, px = qp & 7;
      A2c[(py * 137 + px * 17 + (n >> 2)) * 4 + (n & 3)] =
          (signed char)iclamp(rne4(mx), 0, 7);
    }
  }
  __syncthreads();

  // ---- stage 3a: dw 3x3, 64ch 8x8 (strip of 4) A2 -> Apw3 (MFMA layout) ----
  {
    int cq2 = tid >> 4;                 // 0..15
    int s = tid & 15;
    int y = s >> 1, x0 = (s & 1) << 2;
    int wk[9][4];
#pragma unroll
    for (int t9 = 0; t9 < 9; t9++)
#pragma unroll
      for (int cc = 0; cc < 4; cc++)
        wk[t9][cc] = wq[DW3i + (cq2 * 4 + cc) * 9 + t9];
    int acc[4][4] = {};
#pragma unroll
    for (int ky = 0; ky < 3; ky++) {
      int yy = y + ky - 1;
      if (yy < 0 || yy > 7) continue;
      int rb = yy * 137 + cq2;
      int rd[6];
      rd[0] = (x0 == 4) ? bufBi[rb + (x0 - 1) * 17] : 0;
      rd[1] = bufBi[rb + x0 * 17];
      rd[2] = bufBi[rb + (x0 + 1) * 17];
      rd[3] = bufBi[rb + (x0 + 2) * 17];
      rd[4] = bufBi[rb + (x0 + 3) * 17];
      rd[5] = (x0 == 0) ? bufBi[rb + (x0 + 4) * 17] : 0;
      int e[6][4];
#pragma unroll
      for (int k = 0; k < 6; k++)
#pragma unroll
        for (int cc = 0; cc < 4; cc++) e[k][cc] = (rd[k] >> (8 * cc)) & 0xf;
#pragma unroll
      for (int j = 0; j < 4; j++)
#pragma unroll
        for (int kx = 0; kx < 3; kx++)
#pragma unroll
          for (int cc = 0; cc < 4; cc++)
            acc[j][cc] += e[j + kx][cc] * wk[ky * 3 + kx][cc];
    }
#pragma unroll
    for (int j = 0; j < 4; j++) {
      int pk = 0;
#pragma unroll
      for (int cc = 0; cc < 4; cc++)
        pk |= (iclamp(rne4(acc[j][cc]), -8, 7) & 0xff) << (8 * cc);
      bufAi[(y * 8 + x0 + j) * 18 + cq2] = pk;   // byte = pos*72 + ch
    }
  }
  __syncthreads();

  // ---- stage 3b: pw3 via MFMA (K=64 as 2x K=32) + global max pool -> fcin ----
  {
    const int w = tid >> 6, lane = tid & 63;
    const int lm = lane & 15, kg = lane >> 4;
    const signed char* Ab = (const signed char*)bufAi;
    signed char* fcin = (signed char*)bufBi;
#pragma unroll
    for (int h = 0; h < 2; h++) {
      int nt = w * 2 + h;
      const long b0 = *(const long*)(wq + PW3Fb + (nt * 2 + 0) * 128 + lane * 2);
      const long b1 = *(const long*)(wq + PW3Fb + (nt * 2 + 1) * 128 + lane * 2);
      int mx = -1000000;
#pragma unroll
      for (int mt = 0; mt < 4; mt++) {
        int m = mt * 16 + lm;
        long a0 = *(const long*)(Ab + m * 72 + kg * 8);
        long a1 = *(const long*)(Ab + m * 72 + 32 + kg * 8);
        v4i d = __builtin_amdgcn_mfma_i32_16x16x32_i8(a0, b0, (v4i){0, 0, 0, 0},
                                                      0, 0, 0);
        d = __builtin_amdgcn_mfma_i32_16x16x32_i8(a1, b1, d, 0, 0, 0);
        int t4 = max(max(d[0], d[1]), max(d[2], d[3]));
        mx = mx > t4 ? mx : t4;
      }
      mx = max(mx, __shfl_xor(mx, 16));
      mx = max(mx, __shfl_xor(mx, 32));
      if (lane < 16)
        fcin[nt * 16 + lm] = (signed char)iclamp(rne4(mx), 0, 7);
    }
  }
  __syncthreads();

  // ---- fc1: 128 -> 256 (sdot4) fcin(bufB) -> fc2in(bufA bytes) ----
  {
    const int4* wp = (const int4*)(wq + WC1p + tid * 32);
    const int4* mp = (const int4*)bufBi;
    int acc = 0;
#pragma unroll
    for (int rI = 0; rI < 8; rI++) {
      int4 a = mp[rI]; int4 w = wp[rI];
      acc = dot4(a.x, w.x, acc); acc = dot4(a.y, w.y, acc);
      acc = dot4(a.z, w.z, acc); acc = dot4(a.w, w.w, acc);
    }
    ((signed char*)bufAi)[tid] = (signed char)iclamp(rne4(acc), 0, 7);
  }
  __syncthreads();

  // ---- fc2: 256 -> 10 + int8 output quant ----
  if (tid < 80) {
    int k = tid >> 3, j = tid & 7;
    const int4* wp = (const int4*)(wq + WC2p + k * 64 + j * 8);
    int4 w0v = wp[0], w1v = wp[1];
    const int4* ap = (const int4*)bufAi;
    int4 A0 = ap[j * 2], A1 = ap[j * 2 + 1];
    int acc = dot4(A0.x, w0v.x, 0);
    acc = dot4(A0.y, w0v.y, acc); acc = dot4(A0.z, w0v.z, acc);
    acc = dot4(A0.w, w0v.w, acc);
    acc = dot4(A1.x, w1v.x, acc); acc = dot4(A1.y, w1v.y, acc);
    acc = dot4(A1.z, w1v.z, acc); acc = dot4(A1.w, w1v.w, acc);
    s_red[tid] = acc;
  }
  __syncthreads();
  if (tid < 10) {
    int acc = 0;
#pragma unroll
    for (int j = 0; j < 8; j++) acc += s_red[tid * 8 + j];
    int code = iclamp(2 * acc, -128, 127);
    out[(size_t)img * 10 + tid] = (float)code * 0.0625f;
  }
}

extern "C" void kernel_launch(void* const* d_in, const int* in_sizes, int n_in,
                              void* d_out, int out_size, void* d_ws, size_t ws_size,
                              hipStream_t stream) {
  const float* x   = (const float*)d_in[0];
  const float* w0  = (const float*)d_in[1];
  const float* dw1 = (const float*)d_in[2];
  const float* pw1 = (const float*)d_in[3];
  const float* dw2 = (const float*)d_in[4];
  const float* pw2 = (const float*)d_in[5];
  const float* dw3 = (const float*)d_in[6];
  const float* pw3 = (const float*)d_in[7];
  const float* wc1 = (const float*)d_in[8];
  const float* wc2 = (const float*)d_in[9];
  int*   wsq = (int*)d_ws;     // 14948 ints = 59.8 KB (L2-resident)
  float* out = (float*)d_out;  // (1024,10,1,1) fp32

  prep_weights<<<(WTOT + 255) / 256, 256, 0, stream>>>(
      w0, dw1, pw1, dw2, pw2, dw3, pw3, wc1, wc2, wsq);
  fused_net<<<1024, 256, 0, stream>>>(x, wsq, out);
}

// Round 5
// 95.968 us; speedup vs baseline: 3.1377x; 1.0199x over previous
//
#include <hip/hip_runtime.h>

typedef int v4i __attribute__((ext_vector_type(4)));

// ---- weight workspace layout (int32 units) ----
#define W0i   0       // 9   int codes (8-bit, -128..127)
#define DW1i  9       // 27  int codes (4-bit)
#define PW1i  36      // 96  int codes
#define DW2i  132     // 288 int codes (legacy)
#define DW3i  420     // 576 int codes (legacy)
#define PW2p  996     // 512  packed i8x4 (legacy)
#define PW3p  1508    // 2048 packed (legacy)
#define WC1p  3556    // 8192 packed:  [o=0..255][k4=0..31]
#define WC2p  11748   // 640  packed:  [o=0..9][k4=0..63]
#define PW2Fb 12388   // 512  dwords: pw2 B-frags [nt(4)][lane(64)][dw(2)]
#define PW3Fb 12900   // 2048 dwords: pw3 B-frags [nt(8)*2+kh][lane(64)][dw(2)]
#define DW2pk 14948   // 144  dwords: dw2 pk16 pairs [cq(8)][t9(9)][e/o]
#define DW3pk 15092   // 288  dwords: dw3 pk16 pairs [cq(16)][t9(9)][e/o]
#define WTOT  15380

__device__ __forceinline__ int iclamp(int v, int lo, int hi) {
  return v < lo ? lo : (v > hi ? hi : v);
}
// round-half-even of a/4 and a/32 (exact jnp.round semantics, all-integer)
__device__ __forceinline__ int rne4(int a) {
  return (a + 1 + ((a >> 2) & 1)) >> 2;
}
__device__ __forceinline__ int rne32(int a) {
  return (a + 15 + ((a >> 5) & 1)) >> 5;
}

__device__ __forceinline__ int dot4(int a, int b, int c) {
#if defined(__has_builtin) && __has_builtin(__builtin_amdgcn_sdot4)
  return __builtin_amdgcn_sdot4(a, b, c, false);
#else
  c += ((a << 24) >> 24) * ((b << 24) >> 24);
  c += ((a << 16) >> 24) * ((b << 16) >> 24);
  c += ((a <<  8) >> 24) * ((b <<  8) >> 24);
  c += (a >> 24) * (b >> 24);
  return c;
#endif
}

__device__ __forceinline__ int alignb(int hi, int lo, int sh) {
#if defined(__has_builtin) && __has_builtin(__builtin_amdgcn_alignbyte)
  return __builtin_amdgcn_alignbyte(hi, lo, sh);
#else
  return (int)(((((unsigned long long)(unsigned)hi) << 32) |
                (unsigned)lo) >> (8 * sh));
#endif
}

__device__ __forceinline__ int pack3(int a, int b, int c) {
  return (a & 0xff) | ((b & 0xff) << 8) | ((c & 0xff) << 16);
}

// ---- VOP3P packed-i16 helpers (2 channels per dword, 16-bit lanes) ----
__device__ __forceinline__ int pk_mad16(int a, int b, int c) {
  int d;
  asm("v_pk_mad_i16 %0, %1, %2, %3" : "=v"(d) : "v"(a), "v"(b), "v"(c));
  return d;
}
__device__ __forceinline__ int pk_add16(int a, int b) {
  int d;
  asm("v_pk_add_i16 %0, %1, %2" : "=v"(d) : "v"(a), "v"(b));
  return d;
}
__device__ __forceinline__ int pk_ashr16(int sh, int a) {
  int d;
  asm("v_pk_ashrrev_i16 %0, %1, %2" : "=v"(d) : "v"(sh), "v"(a));
  return d;
}
__device__ __forceinline__ int pk_max16(int a, int b) {
  int d;
  asm("v_pk_max_i16 %0, %1, %2" : "=v"(d) : "v"(a), "v"(b));
  return d;
}
__device__ __forceinline__ int pk_min16(int a, int b) {
  int d;
  asm("v_pk_min_i16 %0, %1, %2" : "=v"(d) : "v"(a), "v"(b));
  return d;
}
// packed rne(a/4) then clamp to [-8,7], per 16-bit lane (exact RNE, incl. negatives)
__device__ __forceinline__ int rne4s_pk(int a) {
  const int sh = 0x00020002, one = 0x00010001;
  int t = pk_ashr16(sh, a);
  t &= one;
  t += one;                       // lanes hold 1 or 2 -> no cross-lane carry
  int s4 = pk_add16(a, t);
  int r = pk_ashr16(sh, s4);
  r = pk_max16(r, (int)0xFFF8FFF8);
  r = pk_min16(r, 0x00070007);
  return r;
}

__device__ __forceinline__ int max4(v4i d) {
  int a = d[0] > d[1] ? d[0] : d[1];
  int b = d[2] > d[3] ? d[2] : d[3];
  return a > b ? a : b;
}

__global__ __launch_bounds__(256) void prep_weights(
    const float* __restrict__ w0,  const float* __restrict__ dw1,
    const float* __restrict__ pw1, const float* __restrict__ dw2,
    const float* __restrict__ pw2, const float* __restrict__ dw3,
    const float* __restrict__ pw3, const float* __restrict__ wc1,
    const float* __restrict__ wc2, int* __restrict__ ws) {
  int t = blockIdx.x * blockDim.x + threadIdx.x;
  if (t >= WTOT) return;
  if (t < PW2p) {
    float w; int lo = -8, hi = 7;
    if (t < DW1i)      { w = w0[t];        lo = -128; hi = 127; }
    else if (t < PW1i)   w = dw1[t - DW1i];
    else if (t < DW2i)   w = pw1[t - PW1i];
    else if (t < DW3i)   w = dw2[t - DW2i];
    else                 w = dw3[t - DW3i];
    ws[t] = iclamp((int)rintf(w * 4.f), lo, hi);
  } else if (t < PW2Fb) {
    const float* src;
    if (t < WC1p) {
      if (t < PW3p) src = pw2 + (t - PW2p) * 4;
      else          src = pw3 + (t - PW3p) * 4;
    } else {
      if (t < WC2p) src = wc1 + (t - WC1p) * 4;
      else          src = wc2 + (t - WC2p) * 4;
    }
    int p = 0;
#pragma unroll
    for (int b = 0; b < 4; b++) {
      int c = iclamp((int)rintf(src[b] * 4.f), -8, 7);
      p |= (c & 0xff) << (8 * b);
    }
    ws[t] = p;
  } else if (t < PW3Fb) {
    // pw2 MFMA B-fragment: B[k][n], n=nt*16+(lane&15), k=(lane>>4)*8+dw*4+b
    int i = t - PW2Fb;
    int nt = i >> 7, r = i & 127, lane = r >> 1, dw = r & 1;
    int n = nt * 16 + (lane & 15);
    int kb = (lane >> 4) * 8 + dw * 4;
    int p = 0;
#pragma unroll
    for (int b = 0; b < 4; b++) {
      int c = iclamp((int)rintf(pw2[n * 32 + kb + b] * 4.f), -8, 7);
      p |= (c & 0xff) << (8 * b);
    }
    ws[t] = p;
  } else if (t < DW2pk) {
    // pw3 MFMA B-fragment: k = kh*32 + (lane>>4)*8 + dw*4 + b
    int i = t - PW3Fb;
    int g = i >> 7, r = i & 127, lane = r >> 1, dw = r & 1;
    int nt = g >> 1, kh = g & 1;
    int n = nt * 16 + (lane & 15);
    int kb = kh * 32 + (lane >> 4) * 8 + dw * 4;
    int p = 0;
#pragma unroll
    for (int b = 0; b < 4; b++) {
      int c = iclamp((int)rintf(pw3[n * 64 + kb + b] * 4.f), -8, 7);
      p |= (c & 0xff) << (8 * b);
    }
    ws[t] = p;
  } else if (t < DW3pk) {
    // dw2 pk16 weight pairs: [cq][t9][par]: lo16 = ch cq*4+par, hi16 = ch cq*4+2+par
    int i = t - DW2pk;
    int cq = i / 18, r = i - cq * 18, t9 = r >> 1, par = r & 1;
    int wl = iclamp((int)rintf(dw2[(cq * 4 + par) * 9 + t9] * 4.f), -8, 7);
    int wh = iclamp((int)rintf(dw2[(cq * 4 + 2 + par) * 9 + t9] * 4.f), -8, 7);
    ws[t] = (wl & 0xFFFF) | (wh << 16);
  } else {
    // dw3 pk16 weight pairs
    int i = t - DW3pk;
    int cq = i / 18, r = i - cq * 18, t9 = r >> 1, par = r & 1;
    int wl = iclamp((int)rintf(dw3[(cq * 4 + par) * 9 + t9] * 4.f), -8, 7);
    int wh = iclamp((int)rintf(dw3[(cq * 4 + 2 + par) * 9 + t9] * 4.f), -8, 7);
    ws[t] = (wl & 0xFFFF) | (wh << 16);
  }
}

// LDS layouts (unchanged from R4):
//  A0:  [c][256] dwords                       (stage0 -> 1b)   bufA
//  B0:  [c][256] dwords                       (1b -> 1c)       bufB
//  A1:  dword = y*149 + x*9 + cq   (16x16)    (1c -> 2a)       bufA
//  B1:  dword = y*162 + x*10 + cq  (16x16)    (2a -> 2aT)      bufB
//  Apw2: MFMA A, byte = m*40 + k, m=qp*4+d, k=ch (K=32)        bufA
//  A2:  dword = py*137 + px*17 + oq (8x8)     (2b -> 3a)       bufB
//  Apw3: MFMA A, byte = pos*72 + k, k=ch (K=64)                bufA
//  fcin: bytes 0..127                          (3b -> fc1)     bufB
__global__ __launch_bounds__(256, 4) void fused_net(
    const float* __restrict__ x,   // (1024,3,32,32)
    const int*   __restrict__ wq,
    float* __restrict__ out)       // (1024,10)
{
  const int img = blockIdx.x;
  const int tid = threadIdx.x;

  __shared__ __align__(16) int bufAi[2560];
  __shared__ __align__(16) int bufBi[2592];
  __shared__ int s_red[256];

  // ---- stage 0: input quant(8b) + 1x1 conv w0 + 4b quant -> A0 ----
  {
    const float* xim = x + (size_t)img * 3072;
    const int p4 = tid * 4;
    float4 v0 = *(const float4*)(xim + p4);
    float4 v1 = *(const float4*)(xim + 1024 + p4);
    float4 v2 = *(const float4*)(xim + 2048 + p4);
    int w[9];
#pragma unroll
    for (int i = 0; i < 9; i++) w[i] = wq[W0i + i];
#define Q8(v) iclamp((int)rintf((v) * 16.f), -128, 127)
    int a0[4] = {Q8(v0.x), Q8(v0.y), Q8(v0.z), Q8(v0.w)};
    int a1[4] = {Q8(v1.x), Q8(v1.y), Q8(v1.z), Q8(v1.w)};
    int a2[4] = {Q8(v2.x), Q8(v2.y), Q8(v2.z), Q8(v2.w)};
#undef Q8
#pragma unroll
    for (int o = 0; o < 3; o++) {
      int pk = 0;
#pragma unroll
      for (int j = 0; j < 4; j++) {
        int s = a0[j] * w[o * 3] + a1[j] * w[o * 3 + 1] + a2[j] * w[o * 3 + 2];
        pk |= (iclamp(rne32(s), -8, 7) & 0xff) << (8 * j);
      }
      bufAi[o * 256 + tid] = pk;
    }
  }
  __syncthreads();

  // ---- stage 1b: dw 3x3, 3ch 32x32 (strip of 4, alignbyte+sdot4) -> B0 ----
  {
    const int y = tid >> 3, q = tid & 7;
#pragma unroll
    for (int c = 0; c < 3; c++) {
      int wr[3];
#pragma unroll
      for (int r = 0; r < 3; r++)
        wr[r] = pack3(wq[DW1i + c * 9 + r * 3], wq[DW1i + c * 9 + r * 3 + 1],
                      wq[DW1i + c * 9 + r * 3 + 2]);
      const int* ap = bufAi + c * 256;
      int acc0 = 0, acc1 = 0, acc2 = 0, acc3 = 0;
#pragma unroll
      for (int ky = 0; ky < 3; ky++) {
        int yy = y + ky - 1;
        if (yy < 0 || yy > 31) continue;
        int base = yy * 8 + q;
        int dC = ap[base];
        int dL = q ? ap[base - 1] : 0;
        int dR = (q < 7) ? ap[base + 1] : 0;
        int w = wr[ky];
        acc0 = dot4(alignb(dC, dL, 3), w, acc0);
        acc1 = dot4(dC, w, acc1);
        acc2 = dot4(alignb(dR, dC, 1), w, acc2);
        acc3 = dot4(alignb(dR, dC, 2), w, acc3);
      }
      int pk = (iclamp(rne4(acc0), -8, 7) & 0xff) |
               ((iclamp(rne4(acc1), -8, 7) & 0xff) << 8) |
               ((iclamp(rne4(acc2), -8, 7) & 0xff) << 16) |
               ((iclamp(rne4(acc3), -8, 7) & 0xff) << 24);
      bufBi[c * 256 + tid] = pk;
    }
  }
  __syncthreads();

  // ---- stage 1c: pw1 (3->32, sdot4) + relu-q + pool2 + requant -> A1 ----
  {
    const int py = tid >> 4, px = tid & 15;
    const unsigned char* bB = (const unsigned char*)bufBi;
    unsigned u[3][2];
#pragma unroll
    for (int c = 0; c < 3; c++)
#pragma unroll
      for (int dy = 0; dy < 2; dy++)
        u[c][dy] = *(const unsigned short*)(bB + c * 1024 +
                                            (2 * py + dy) * 32 + 2 * px);
    int a[4];
#pragma unroll
    for (int d = 0; d < 4; d++) {
      int dy = d >> 1, dx = d & 1;
      unsigned t1 = __builtin_amdgcn_perm(u[1][dy], u[0][dy],
                                          0x0C0C0000u | ((4 + dx) << 8) | dx);
      a[d] = (int)__builtin_amdgcn_perm(u[2][dy], t1,
                                        0x0C000100u | ((4 + dx) << 16));
    }
#pragma unroll
    for (int it = 0; it < 8; it++) {
      int pk = 0;
#pragma unroll
      for (int j = 0; j < 4; j++) {
        int o = it * 4 + j;
        int wpk = pack3(wq[PW1i + o * 3], wq[PW1i + o * 3 + 1],
                        wq[PW1i + o * 3 + 2]);
        int m0 = dot4(a[0], wpk, 0), m1 = dot4(a[1], wpk, 0);
        int m2 = dot4(a[2], wpk, 0), m3 = dot4(a[3], wpk, 0);
        int mx = max(max(m0, m1), max(m2, m3));
        pk |= iclamp(rne4(mx), 0, 7) << (8 * j);
      }
      bufAi[py * 149 + px * 9 + it] = pk;
    }
  }
  __syncthreads();

  // ---- stage 2a: dw 3x3, 32ch 16x16, pk_mad_i16 (strip of 4) A1 -> B1 ----
  for (int it2 = 0; it2 < 2; it2++) {
    int idx = tid + 256 * it2;
    int cq = __builtin_amdgcn_readfirstlane(idx >> 6);   // wave-uniform
    int s = idx & 63;
    int y = s >> 2, x0 = (s & 3) << 2;
    int we[9], wo[9];
    {
      const int2* wp = (const int2*)(wq + DW2pk + cq * 18);
#pragma unroll
      for (int t9 = 0; t9 < 9; t9++) { int2 v = wp[t9]; we[t9] = v.x; wo[t9] = v.y; }
    }
    int acce[4] = {}, acco[4] = {};
#pragma unroll
    for (int ky = 0; ky < 3; ky++) {
      int yy = y + ky - 1;
      if (yy < 0 || yy > 15) continue;
      int rb = yy * 149 + cq;
      int rd[6];
      rd[0] = (x0 > 0) ? bufAi[rb + (x0 - 1) * 9] : 0;
      rd[1] = bufAi[rb + x0 * 9];
      rd[2] = bufAi[rb + (x0 + 1) * 9];
      rd[3] = bufAi[rb + (x0 + 2) * 9];
      rd[4] = bufAi[rb + (x0 + 3) * 9];
      rd[5] = (x0 < 12) ? bufAi[rb + (x0 + 4) * 9] : 0;
      int ee[6], eo[6];
#pragma unroll
      for (int k = 0; k < 6; k++) {
        ee[k] = rd[k] & 0x000F000F;
        eo[k] = (rd[k] >> 8) & 0x000F000F;
      }
#pragma unroll
      for (int j = 0; j < 4; j++)
#pragma unroll
        for (int kx = 0; kx < 3; kx++) {
          acce[j] = pk_mad16(ee[j + kx], we[ky * 3 + kx], acce[j]);
          acco[j] = pk_mad16(eo[j + kx], wo[ky * 3 + kx], acco[j]);
        }
    }
#pragma unroll
    for (int j = 0; j < 4; j++) {
      int re = rne4s_pk(acce[j]);
      int ro = rne4s_pk(acco[j]);
      bufBi[y * 162 + (x0 + j) * 10 + cq] =
          (re & 0x00FF00FF) | ((ro & 0x00FF00FF) << 8);
    }
  }
  __syncthreads();

  // ---- stage 2aT: transpose B1 -> Apw2 (MFMA A layout, pool-ordered m) ----
#pragma unroll
  for (int i = 0; i < 4; i++) {
    int id = tid + 256 * i;
    int m = id >> 2, c2 = id & 3;
    int qp = m >> 2, d = m & 3;
    int sy = ((qp >> 3) << 1) + (d >> 1);
    int sx = ((qp & 7) << 1) + (d & 1);
    long v = *(const long*)(bufBi + sy * 162 + sx * 10 + c2 * 2);
    *(long*)(bufAi + m * 10 + c2 * 2) = v;
  }
  __syncthreads();

  // ---- stage 2b: pw2 via MFMA i32_16x16x32_i8, fused relu+pool2 -> A2 ----
  // each wave: 2 nt tiles x 8 mt tiles; A-frags reused across the 2 nt.
  {
    const int w = tid >> 6, lane = tid & 63;
    const int lm = lane & 15, kg = lane >> 4;
    const int ntp = (w & 1) * 2;          // nt base: 0 or 2
    const int mtb = (w >> 1) * 8;         // mt half: 0 or 8
    const long bw0 = *(const long*)(wq + PW2Fb + (ntp * 64 + lane) * 2);
    const long bw1 = *(const long*)(wq + PW2Fb + ((ntp + 1) * 64 + lane) * 2);
    const signed char* Ab = (const signed char*)bufAi;
    signed char* A2c = (signed char*)bufBi;
    const int n0 = ntp * 16 + lm, n1 = (ntp + 1) * 16 + lm;
#pragma unroll 4
    for (int mt = mtb; mt < mtb + 8; mt++) {
      int m = mt * 16 + lm;
      long av = *(const long*)(Ab + m * 40 + kg * 8);
      v4i d0 = __builtin_amdgcn_mfma_i32_16x16x32_i8(av, bw0, (v4i){0, 0, 0, 0},
                                                     0, 0, 0);
      v4i d1 = __builtin_amdgcn_mfma_i32_16x16x32_i8(av, bw1, (v4i){0, 0, 0, 0},
                                                     0, 0, 0);
      int qp = mt * 4 + kg;
      int py = qp >> 3, px = qp & 7;
      int bb = (py * 137 + px * 17) * 4;
      A2c[bb + n0] = (signed char)iclamp(rne4(max4(d0)), 0, 7);
      A2c[bb + n1] = (signed char)iclamp(rne4(max4(d1)), 0, 7);
    }
  }
  __syncthreads();

  // ---- stage 3a: dw 3x3, 64ch 8x8, pk_mad_i16 (strip of 4) A2 -> Apw3 ----
  {
    int cq2 = tid >> 4;                 // 0..15 (per-thread VMEM pk weights)
    int s = tid & 15;
    int y = s >> 1, x0 = (s & 1) << 2;
    int we[9], wo[9];
    {
      const int2* wp = (const int2*)(wq + DW3pk + cq2 * 18);
#pragma unroll
      for (int t9 = 0; t9 < 9; t9++) { int2 v = wp[t9]; we[t9] = v.x; wo[t9] = v.y; }
    }
    int acce[4] = {}, acco[4] = {};
#pragma unroll
    for (int ky = 0; ky < 3; ky++) {
      int yy = y + ky - 1;
      if (yy < 0 || yy > 7) continue;
      int rb = yy * 137 + cq2;
      int rd[6];
      rd[0] = (x0 == 4) ? bufBi[rb + (x0 - 1) * 17] : 0;
      rd[1] = bufBi[rb + x0 * 17];
      rd[2] = bufBi[rb + (x0 + 1) * 17];
      rd[3] = bufBi[rb + (x0 + 2) * 17];
      rd[4] = bufBi[rb + (x0 + 3) * 17];
      rd[5] = (x0 == 0) ? bufBi[rb + (x0 + 4) * 17] : 0;
      int ee[6], eo[6];
#pragma unroll
      for (int k = 0; k < 6; k++) {
        ee[k] = rd[k] & 0x000F000F;
        eo[k] = (rd[k] >> 8) & 0x000F000F;
      }
#pragma unroll
      for (int j = 0; j < 4; j++)
#pragma unroll
        for (int kx = 0; kx < 3; kx++) {
          acce[j] = pk_mad16(ee[j + kx], we[ky * 3 + kx], acce[j]);
          acco[j] = pk_mad16(eo[j + kx], wo[ky * 3 + kx], acco[j]);
        }
    }
#pragma unroll
    for (int j = 0; j < 4; j++) {
      int re = rne4s_pk(acce[j]);
      int ro = rne4s_pk(acco[j]);
      bufAi[(y * 8 + x0 + j) * 18 + cq2] =
          (re & 0x00FF00FF) | ((ro & 0x00FF00FF) << 8);
    }
  }
  __syncthreads();

  // ---- stage 3b: pw3 via MFMA (K=64 as 2x K=32) + global max pool -> fcin ----
  // each wave: 2 nt tiles; A-frags loaded once per mt, reused across nt.
  {
    const int w = tid >> 6, lane = tid & 63;
    const int lm = lane & 15, kg = lane >> 4;
    const signed char* Ab = (const signed char*)bufAi;
    signed char* fcin = (signed char*)bufBi;
    long b0v[2], b1v[2];
#pragma unroll
    for (int h = 0; h < 2; h++) {
      int nt = w * 2 + h;
      b0v[h] = *(const long*)(wq + PW3Fb + (nt * 2 + 0) * 128 + lane * 2);
      b1v[h] = *(const long*)(wq + PW3Fb + (nt * 2 + 1) * 128 + lane * 2);
    }
    int mx[2] = {-1000000, -1000000};
#pragma unroll
    for (int mt = 0; mt < 4; mt++) {
      int m = mt * 16 + lm;
      long a0 = *(const long*)(Ab + m * 72 + kg * 8);
      long a1 = *(const long*)(Ab + m * 72 + 32 + kg * 8);
#pragma unroll
      for (int h = 0; h < 2; h++) {
        v4i d = __builtin_amdgcn_mfma_i32_16x16x32_i8(a0, b0v[h],
                                                      (v4i){0, 0, 0, 0}, 0, 0, 0);
        d = __builtin_amdgcn_mfma_i32_16x16x32_i8(a1, b1v[h], d, 0, 0, 0);
        int t4 = max4(d);
        mx[h] = mx[h] > t4 ? mx[h] : t4;
      }
    }
#pragma unroll
    for (int h = 0; h < 2; h++) {
      int red = max(mx[h], __shfl_xor(mx[h], 16));
      red = max(red, __shfl_xor(red, 32));
      if (lane < 16)
        fcin[(w * 2 + h) * 16 + lm] = (signed char)iclamp(rne4(red), 0, 7);
    }
  }
  __syncthreads();

  // ---- fc1: 128 -> 256 (sdot4) fcin(bufB) -> fc2in(bufA bytes) ----
  {
    const int4* wp = (const int4*)(wq + WC1p + tid * 32);
    const int4* mp = (const int4*)bufBi;
    int acc = 0;
#pragma unroll
    for (int rI = 0; rI < 8; rI++) {
      int4 a = mp[rI]; int4 w = wp[rI];
      acc = dot4(a.x, w.x, acc); acc = dot4(a.y, w.y, acc);
      acc = dot4(a.z, w.z, acc); acc = dot4(a.w, w.w, acc);
    }
    ((signed char*)bufAi)[tid] = (signed char)iclamp(rne4(acc), 0, 7);
  }
  __syncthreads();

  // ---- fc2: 256 -> 10 + int8 output quant ----
  if (tid < 80) {
    int k = tid >> 3, j = tid & 7;
    const int4* wp = (const int4*)(wq + WC2p + k * 64 + j * 8);
    int4 w0v = wp[0], w1v = wp[1];
    const int4* ap = (const int4*)bufAi;
    int4 A0 = ap[j * 2], A1 = ap[j * 2 + 1];
    int acc = dot4(A0.x, w0v.x, 0);
    acc = dot4(A0.y, w0v.y, acc); acc = dot4(A0.z, w0v.z, acc);
    acc = dot4(A0.w, w0v.w, acc);
    acc = dot4(A1.x, w1v.x, acc); acc = dot4(A1.y, w1v.y, acc);
    acc = dot4(A1.z, w1v.z, acc); acc = dot4(A1.w, w1v.w, acc);
    s_red[tid] = acc;
  }
  __syncthreads();
  if (tid < 10) {
    int acc = 0;
#pragma unroll
    for (int j = 0; j < 8; j++) acc += s_red[tid * 8 + j];
    int code = iclamp(2 * acc, -128, 127);
    out[(size_t)img * 10 + tid] = (float)code * 0.0625f;
  }
}

extern "C" void kernel_launch(void* const* d_in, const int* in_sizes, int n_in,
                              void* d_out, int out_size, void* d_ws, size_t ws_size,
                              hipStream_t stream) {
  const float* x   = (const float*)d_in[0];
  const float* w0  = (const float*)d_in[1];
  const float* dw1 = (const float*)d_in[2];
  const float* pw1 = (const float*)d_in[3];
  const float* dw2 = (const float*)d_in[4];
  const float* pw2 = (const float*)d_in[5];
  const float* dw3 = (const float*)d_in[6];
  const float* pw3 = (const float*)d_in[7];
  const float* wc1 = (const float*)d_in[8];
  const float* wc2 = (const float*)d_in[9];
  int*   wsq = (int*)d_ws;     // 15380 ints = 61.5 KB (L2-resident)
  float* out = (float*)d_out;  // (1024,10,1,1) fp32

  prep_weights<<<(WTOT + 255) / 256, 256, 0, stream>>>(
      w0, dw1, pw1, dw2, pw2, dw3, pw3, wc1, wc2, wsq);
  fused_net<<<1024, 256, 0, stream>>>(x, wsq, out);
}